// Round 1
// baseline (91.628 us; speedup 1.0000x reference)
//
#include <hip/hip_runtime.h>

// Batched 10-qubit statevector simulator — one 64-lane wave per sample.
// State: 1024 complex amps; s = (r<<6)|lane; qubit q <-> bit (9-q):
//   qubits 0..3 -> register-index bits (16 regs per lane)
//   qubits 4..9 -> lane bits (butterfly exchanges)
// R14 (38.5us steady): state packed as f16x2 (re,im) in one VGPR per amp;
//   packed math -> v_pk_fma_f16; coefficients fp32 (sincos + readlane);
//   layer-0 product construction; ring-4 folded into epilogue parities.
// R18 (this round): replace ds_bpermute with v_permlane16/32_swap_b32 for
//   the M=16/32 gate butterflies and the epilogue 16/32 folds. permlane is
//   VALU (no DS round-trip, no lgkmcnt); m255 measured 1.20x vs bperm for
//   the xor-32 exchange even in a VALU-bound regime. swap(v,v) returns
//   ({lo,lo},{hi,hi}); gate path selects by lane half (1 cndmask); epilogue
//   reduction uses ret0+ret1 == z + z^M directly (no select, convention-
//   free). Ring keeps bperm: lane^(lane>>1) is a general permutation.
//   DS ops/wave: 200 -> 64. Predict: DS 22%->~8%, waitcnt down, steady
//   ~38.5 -> ~34us.
// Ladder: 137us (R0 naive-reg) -> 78 (lane-parallel coeffs via readlane +
//   launch_bounds(256,4)) -> 64 (packed f32 VOP3P) -> 48 (DPP for masks
//   1,2,8) -> 44.8 (layer-0 product construction + ring-4 folded into
//   epilogue parities) -> 41.8 (mask-4 as 2-DPP chain) -> 38.5 (f16x2).
// Falsified alternatives (all neutral or worse): extra waves/sample (R8),
//   DS phase staggering (R11), ring folding into gate coeffs (R12), rolled
//   layer loop (R13), __hfma2 forcing (R15), op_sel inline asm + packed
//   coeff precompute (R16), 2 samples/wave ILP (R17).

constexpr int NQ  = 10;
constexpr int NL  = 5;
constexpr int OBS = 10;

typedef float        f2 __attribute__((ext_vector_type(2)));
typedef _Float16     h2 __attribute__((ext_vector_type(2)));
typedef unsigned int u2 __attribute__((ext_vector_type(2)));

__device__ __forceinline__ float readlane_f(float v, int l) {
    return __int_as_float(__builtin_amdgcn_readlane(__float_as_int(v), l));
}
__device__ __forceinline__ int h2_to_i(h2 v) { int i; __builtin_memcpy(&i, &v, 4); return i; }
__device__ __forceinline__ h2  i_to_h2(int i) { h2 v; __builtin_memcpy(&v, &i, 4); return v; }

__device__ __forceinline__ h2 bperm_h2(int byte_addr, h2 v) {
    return i_to_h2(__builtin_amdgcn_ds_bpermute(byte_addr, h2_to_i(v)));
}
template <int CTRL>
__device__ __forceinline__ h2 dpp_h2(h2 v) {
    return i_to_h2(__builtin_amdgcn_update_dpp(0, h2_to_i(v), CTRL, 0xF, 0xF, true));
}

#if __has_builtin(__builtin_amdgcn_permlane16_swap) && __has_builtin(__builtin_amdgcn_permlane32_swap)
#define HAVE_PERMLANE_SWAP 1
#else
#define HAVE_PERMLANE_SWAP 0
#endif

// xor-exchange across lanes; M compile-time -> branches fold.
// permlane*_swap(v, v) convention: ret[0] = low-half content replicated
// into both halves ({lo,lo} / even-rows), ret[1] = high-half content
// ({hi,hi} / odd-rows). Lane in HIGH half needs LOW content -> hi ? r0 : r1.
__device__ __forceinline__ h2 xor_lane(h2 v, int M, bool hi16, bool hi32,
                                       int a16, int a32) {
    switch (M) {
    case 1:  return dpp_h2<0xB1>(v);               // quad_perm [1,0,3,2]
    case 2:  return dpp_h2<0x4E>(v);               // quad_perm [2,3,0,1]
    case 8:  return dpp_h2<0x128>(v);              // row_ror:8 == lane^8
    case 4:  return dpp_h2<0x141>(dpp_h2<0x1B>(v)); // xor3 ∘ xor7 = xor4
    case 16:
#if HAVE_PERMLANE_SWAP
    {
        u2 r = __builtin_amdgcn_permlane16_swap(
            (unsigned)h2_to_i(v), (unsigned)h2_to_i(v), false, false);
        return hi16 ? i_to_h2((int)r[0]) : i_to_h2((int)r[1]);
    }
#else
        return bperm_h2(a16, v);
#endif
    default:                                        // 32
#if HAVE_PERMLANE_SWAP
    {
        u2 r = __builtin_amdgcn_permlane32_swap(
            (unsigned)h2_to_i(v), (unsigned)h2_to_i(v), false, false);
        return hi32 ? i_to_h2((int)r[0]) : i_to_h2((int)r[1]);
    }
#else
        return bperm_h2(a32, v);
#endif
    }
}

// z + z[lane^16] / z + z[lane^32] for EVERY lane, convention-free:
// ret0 + ret1 == v[lane&~M] + v[lane|M] whichever order the halves land in.
__device__ __forceinline__ float fold16_f(float z, int a16) {
#if HAVE_PERMLANE_SWAP
    u2 r = __builtin_amdgcn_permlane16_swap(
        __float_as_uint(z), __float_as_uint(z), false, false);
    return __uint_as_float(r[0]) + __uint_as_float(r[1]);
#else
    return z + __int_as_float(__builtin_amdgcn_ds_bpermute(a16, __float_as_int(z)));
#endif
}
__device__ __forceinline__ float fold32_f(float z, int a32) {
#if HAVE_PERMLANE_SWAP
    u2 r = __builtin_amdgcn_permlane32_swap(
        __float_as_uint(z), __float_as_uint(z), false, false);
    return __uint_as_float(r[0]) + __uint_as_float(r[1]);
#else
    return z + __int_as_float(__builtin_amdgcn_ds_bpermute(a32, __float_as_int(z)));
#endif
}

__device__ __forceinline__ h2 mk_h2(float a, float b) {
    h2 r; r.x = (_Float16)a; r.y = (_Float16)b; return r;
}

__global__ __launch_bounds__(256, 4) void qsim_kernel(
    const float* __restrict__ x,       // (B, 10)
    const float* __restrict__ isc,     // (5, 20)
    const float* __restrict__ w,       // (5, 20)
    const float* __restrict__ oscale,  // (4)
    float* __restrict__ out,           // (B, 4)
    int B)
{
    const int lane = threadIdx.x & 63;
    const int wid  = (blockIdx.x * blockDim.x + threadIdx.x) >> 6;
    if (wid >= B) return;

    // ---- lane-parallel gate-coefficient computation (gates 0..49), fp32 ----
    float cUR, cUI, cVR, cVI;
    {
        const int g   = (lane < 50) ? lane : 49;
        const int q   = g % 10;
        const int lyr = g / 10;
        const float xq    = x[wid * OBS + q];
        const float alpha = isc[lyr * 2 * NQ + q]      * xq;
        const float beta  = isc[lyr * 2 * NQ + NQ + q] * xq;
        const float gamma = w[lyr * 2 * NQ + q];
        const float delta = w[lyr * 2 * NQ + NQ + q];
        float sa, ca, sp, cp, sd, cd;
        __sincosf(0.5f * alpha,          &sa, &ca);
        __sincosf(0.5f * (beta + gamma), &sp, &cp);
        __sincosf(0.5f * delta,          &sd, &cd);
        const float A = cd * ca, Bt = sd * sa;
        const float C = cd * sa, D  = sd * ca;
        cUR = (A - Bt) * cp;
        cUI = -(A + Bt) * sp;
        cVR = (C + D) * cp;
        cVI = (C - D) * sp;
    }

    // hoisted lane-half predicates + bperm byte-addresses (fallback/ring)
    const bool hi16 = (lane & 16) != 0;
    const bool hi32 = (lane & 32) != 0;
    const int a16 = (lane ^ 16) * 4;
    const int a32 = (lane ^ 32) * 4;
    const int cnot_src  = (lane ^ (lane >> 1));
    const int addr_even = cnot_src * 4;            // r bit0 == 0
    const int addr_odd  = (cnot_src ^ 32) * 4;     // r bit0 == 1 (CNOT(3,4))

    h2 c[16];

    // ===== layer 0: direct product-state construction (fp32 -> f16x2) =====
    // amp(s) = prod_q (bit_q(s) ? v_q : u_q), gate column (u,v)=U|0>.
    {
        float Lr = 1.f, Li = 0.f;
#pragma unroll
        for (int q = 4; q < 10; ++q) {
            const float ur = readlane_f(cUR, q), ui = readlane_f(cUI, q);
            const float vr = readlane_f(cVR, q), vi = readlane_f(cVI, q);
            const int M = 1 << (9 - q);
            const float fr = (lane & M) ? vr : ur;
            const float fi = (lane & M) ? vi : ui;
            const float nr = Lr * fr - Li * fi;
            const float ni = Lr * fi + Li * fr;
            Lr = nr; Li = ni;
        }
        f2 cf[16];
        cf[0] = (f2){Lr, Li};
#pragma unroll
        for (int r = 1; r < 16; ++r) cf[r] = (f2){0.f, 0.f};
#pragma unroll
        for (int q = 3; q >= 0; --q) {
            const int m = 1 << (3 - q);
            const float ur = readlane_f(cUR, q), ui = readlane_f(cUI, q);
            const float vr = readlane_f(cVR, q), vi = readlane_f(cVI, q);
#pragma unroll
            for (int r0 = 0; r0 < 16; ++r0) {
                if (r0 >= m) continue;
                const f2 s = cf[r0];
                cf[r0 | m] = (f2){ s.x*vr - s.y*vi, s.x*vi + s.y*vr };
                cf[r0]     = (f2){ s.x*ur - s.y*ui, s.x*ui + s.y*ur };
            }
        }
#pragma unroll
        for (int r = 0; r < 16; ++r) c[r] = mk_h2(cf[r].x, cf[r].y);
    }

#define SWAPR(i, j) { h2 _t = c[i]; c[i] = c[j]; c[j] = _t; }

    for (int layer = 0; layer < NL; ++layer) {
        const int base = layer * NQ;   // wave-uniform

        // ---- fused single-qubit unitaries (layer 0 done by construction) ----
        if (layer > 0) {
#pragma unroll
            for (int q = 0; q < NQ; ++q) {
                const float ur = readlane_f(cUR, base + q);
                const float ui = readlane_f(cUI, base + q);
                const float vr = readlane_f(cVR, base + q);
                const float vi = readlane_f(cVI, base + q);

                if (q < 4) {
                    // register-bit qubit: pair stride m inside the lane.
                    const h2 kUU  = mk_h2(ur, ur);
                    const h2 kUIm = mk_h2(-ui, ui);
                    const h2 kVVn = mk_h2(-vr, -vr);
                    const h2 kVV  = mk_h2(vr, vr);
                    const h2 kVIm = mk_h2(-vi, vi);
                    const h2 kUIp = mk_h2(ui, -ui);
                    const int m = 1 << (3 - q);
#pragma unroll
                    for (int r0 = 0; r0 < 16; ++r0) {
                        if (r0 & m) continue;
                        const int r1 = r0 | m;
                        const h2 c0 = c[r0], c1 = c[r1];
                        const h2 c0s = c0.yx, c1s = c1.yx;
                        c[r0] = kUU*c0 + kUIm*c0s + kVVn*c1 + kVIm*c1s;
                        c[r1] = kVV*c0 + kVIm*c0s + kUU*c1  + kUIp*c1s;
                    }
                } else {
                    // lane-bit qubit: butterfly exchange with lane^M.
                    const int  M   = 1 << (9 - q);
                    const bool bit = (lane & M) != 0;
                    const float Pi = bit ? -ui : ui;
                    const float Qr = bit ?  vr : -vr;
                    const h2 kUUb = mk_h2(ur, ur);
                    const h2 kPI  = mk_h2(-Pi, Pi);
                    const h2 kQR  = mk_h2(Qr, Qr);
                    const h2 kVIb = mk_h2(-vi, vi);
#pragma unroll
                    for (int r = 0; r < 16; ++r) {
                        const h2 mv = c[r];
                        const h2 pv = xor_lane(mv, M, hi16, hi32, a16, a32);
                        c[r] = kUUb*mv + kPI*mv.yx + kQR*pv + kVIb*pv.yx;
                    }
                }
            }
        }

        // ---- CNOT ring (skipped on last layer; folded into epilogue) ----
        if (layer < NL - 1) {
            // CNOT(0,1): ctrl r-bit3, tgt r-bit2 -> register swap
            SWAPR(8, 12) SWAPR(9, 13) SWAPR(10, 14) SWAPR(11, 15)
            // CNOT(1,2): ctrl r-bit2, tgt r-bit1
            SWAPR(4, 6)  SWAPR(5, 7)  SWAPR(12, 14) SWAPR(13, 15)
            // CNOT(2,3): ctrl r-bit1, tgt r-bit0
            SWAPR(2, 3)  SWAPR(6, 7)  SWAPR(10, 11) SWAPR(14, 15)
            // CNOT(3,4)..(8,9) fused: ONE bpermute per amplitude (f16x2).
            // lane^(lane>>1) is a general permutation — stays on DS.
#pragma unroll
            for (int r = 0; r < 16; ++r) {
                const int addr = (r & 1) ? addr_odd : addr_even;
                c[r] = bperm_h2(addr, c[r]);
            }
            // CNOT(9,0): ctrl lane-bit0, tgt r-bit3 -> cond register swap
            const bool ctl = (lane & 1) != 0;
#pragma unroll
            for (int r = 0; r < 8; ++r) {
                const h2 t0 = c[r], t1 = c[r + 8];
                c[r]     = ctl ? t1 : t0;
                c[r + 8] = ctl ? t0 : t1;
            }
        }
    }

    // ---- epilogue (fp32): <Z_i> after the (virtual) final ring ----
    // (Cb)_0 = q1+..+q9 -> reg bits r2,r1,r0 + all 6 lane bits
    // (Cb)_1 = q0+q1 -> r3,r2 ; (Cb)_2 -> r3,r2,r1 ; (Cb)_3 -> r3..r0
    const float sL = (__popc(lane) & 1) ? -1.f : 1.f;
    float z0 = 0.f, z1 = 0.f, z2 = 0.f, z3 = 0.f;
#pragma unroll
    for (int r = 0; r < 16; ++r) {
        const float cr = (float)c[r].x, ci = (float)c[r].y;
        const float pv  = cr * cr + ci * ci;
        const float pvl = sL * pv;
        z0 += (__popc(r & 7)  & 1) ? -pvl : pvl;
        z1 += (__popc(r & 12) & 1) ? -pv  : pv;
        z2 += (__popc(r & 14) & 1) ? -pv  : pv;
        z3 += (__popc(r & 15) & 1) ? -pv  : pv;
    }
    // f32 xor-lane reduction (DPP for 1,2,4,8; permlane-swap folds for 16,32)
#pragma unroll
    for (int m = 1; m < 64; m <<= 1) {
        if (m == 1)      { z0 += __int_as_float(__builtin_amdgcn_update_dpp(0, __float_as_int(z0), 0xB1, 0xF, 0xF, true));
                           z1 += __int_as_float(__builtin_amdgcn_update_dpp(0, __float_as_int(z1), 0xB1, 0xF, 0xF, true));
                           z2 += __int_as_float(__builtin_amdgcn_update_dpp(0, __float_as_int(z2), 0xB1, 0xF, 0xF, true));
                           z3 += __int_as_float(__builtin_amdgcn_update_dpp(0, __float_as_int(z3), 0xB1, 0xF, 0xF, true)); }
        else if (m == 2) { z0 += __int_as_float(__builtin_amdgcn_update_dpp(0, __float_as_int(z0), 0x4E, 0xF, 0xF, true));
                           z1 += __int_as_float(__builtin_amdgcn_update_dpp(0, __float_as_int(z1), 0x4E, 0xF, 0xF, true));
                           z2 += __int_as_float(__builtin_amdgcn_update_dpp(0, __float_as_int(z2), 0x4E, 0xF, 0xF, true));
                           z3 += __int_as_float(__builtin_amdgcn_update_dpp(0, __float_as_int(z3), 0x4E, 0xF, 0xF, true)); }
        else if (m == 4) { z0 += __int_as_float(__builtin_amdgcn_update_dpp(0, __builtin_amdgcn_update_dpp(0, __float_as_int(z0), 0x1B, 0xF, 0xF, true), 0x141, 0xF, 0xF, true));
                           z1 += __int_as_float(__builtin_amdgcn_update_dpp(0, __builtin_amdgcn_update_dpp(0, __float_as_int(z1), 0x1B, 0xF, 0xF, true), 0x141, 0xF, 0xF, true));
                           z2 += __int_as_float(__builtin_amdgcn_update_dpp(0, __builtin_amdgcn_update_dpp(0, __float_as_int(z2), 0x1B, 0xF, 0xF, true), 0x141, 0xF, 0xF, true));
                           z3 += __int_as_float(__builtin_amdgcn_update_dpp(0, __builtin_amdgcn_update_dpp(0, __float_as_int(z3), 0x1B, 0xF, 0xF, true), 0x141, 0xF, 0xF, true)); }
        else if (m == 8) { z0 += __int_as_float(__builtin_amdgcn_update_dpp(0, __float_as_int(z0), 0x128, 0xF, 0xF, true));
                           z1 += __int_as_float(__builtin_amdgcn_update_dpp(0, __float_as_int(z1), 0x128, 0xF, 0xF, true));
                           z2 += __int_as_float(__builtin_amdgcn_update_dpp(0, __float_as_int(z2), 0x128, 0xF, 0xF, true));
                           z3 += __int_as_float(__builtin_amdgcn_update_dpp(0, __float_as_int(z3), 0x128, 0xF, 0xF, true)); }
        else if (m == 16){ z0 = fold16_f(z0, a16);
                           z1 = fold16_f(z1, a16);
                           z2 = fold16_f(z2, a16);
                           z3 = fold16_f(z3, a16); }
        else             { z0 = fold32_f(z0, a32);
                           z1 = fold32_f(z1, a32);
                           z2 = fold32_f(z2, a32);
                           z3 = fold32_f(z3, a32); }
    }
    if (lane == 0) {
        out[wid * 4 + 0] = z0 * oscale[0];
        out[wid * 4 + 1] = z1 * oscale[1];
        out[wid * 4 + 2] = z2 * oscale[2];
        out[wid * 4 + 3] = z3 * oscale[3];
    }
#undef SWAPR
}

extern "C" void kernel_launch(void* const* d_in, const int* in_sizes, int n_in,
                              void* d_out, int out_size, void* d_ws, size_t ws_size,
                              hipStream_t stream) {
    const float* x      = (const float*)d_in[0];
    const float* isc    = (const float*)d_in[1];
    const float* w      = (const float*)d_in[2];
    const float* oscale = (const float*)d_in[3];
    float* out = (float*)d_out;

    const int B = in_sizes[0] / OBS;             // 4096
    const int threads = 256;                     // 4 waves -> 4 samples per block
    const int blocks = (B * 64 + threads - 1) / threads;
    qsim_kernel<<<blocks, threads, 0, stream>>>(x, isc, w, oscale, out, B);
}

// Round 2
// 87.747 us; speedup vs baseline: 1.0442x; 1.0442x over previous
//
#include <hip/hip_runtime.h>

// Batched 10-qubit statevector simulator — one 64-lane wave per sample.
// State: 1024 complex amps; s = (r<<6)|lane; qubit q <-> bit (9-q):
//   qubits 0..3 -> register-index bits (16 regs per lane)
//   qubits 4..9 -> lane bits (butterfly exchanges)
// R14 (38.5us steady): state packed as f16x2 (re,im) in one VGPR per amp;
//   packed math -> v_pk_fma_f16; coefficients fp32 (sincos + readlane);
//   layer-0 product construction; ring-4 folded into epilogue parities.
// R18 POST-MORTEM (39.5us, regressed): permlane16/32_swap in the GATE path
//   moved 128 DS ops onto the VALU pipe (+128 net issue slots on the
//   bottleneck pipe). DS bpermutes were fully overlapped (16 independent
//   r-chains) -> reverted to bperm for gates. permlane KEPT in the epilogue
//   folds only (latency-exposed tail, no overlap available; semantics
//   verified by R18's pass).
// R19 (this round): cut per-gate constant-fabrication VALU work.
//   (a) lane-parallel PACKED h2 constants (kUU,kUI,kVV,kVI) built once in
//       the prologue; per gate just 4 readlanes -> SGPRs feed v_pk_fma_f16
//       directly (1 SGPR/instr). Negated variants via source fneg ->
//       neg_lo/neg_hi modifiers (free). [No inline asm — R16's confound.]
//   (b) lane-gate sign selection = 2 v_xor with hoisted per-M masks
//       (lane&M ? 0x80008000 : 0), replacing per-gate cndmask chains.
//   (c) epilogue |amp|^2 via v_dot2_f32_f16 (1 instr vs 2 cvt+mul+fma).
//   All bit-exact vs R14 -> absmax unchanged.
// Ladder: 137us (R0 naive-reg) -> 78 (lane-parallel coeffs via readlane +
//   launch_bounds(256,4)) -> 64 (packed f32 VOP3P) -> 48 (DPP for masks
//   1,2,8) -> 44.8 (layer-0 product construction + ring-4 folded into
//   epilogue parities) -> 41.8 (mask-4 as 2-DPP chain) -> 38.5 (f16x2).
// Falsified: extra waves/sample (R8), DS phase staggering (R11), ring
//   folding into gate coeffs (R12), rolled layer loop (R13), __hfma2 (R15),
//   op_sel asm + packed coeffs w/ asm (R16), 2 samples/wave (R17),
//   permlane in hot gate loop (R18: DS->VALU on issue-bound kernel).

constexpr int NQ  = 10;
constexpr int NL  = 5;
constexpr int OBS = 10;

typedef float        f2 __attribute__((ext_vector_type(2)));
typedef _Float16     h2 __attribute__((ext_vector_type(2)));
typedef unsigned int u2 __attribute__((ext_vector_type(2)));

__device__ __forceinline__ float readlane_f(float v, int l) {
    return __int_as_float(__builtin_amdgcn_readlane(__float_as_int(v), l));
}
__device__ __forceinline__ int h2_to_i(h2 v) { int i; __builtin_memcpy(&i, &v, 4); return i; }
__device__ __forceinline__ h2  i_to_h2(int i) { h2 v; __builtin_memcpy(&v, &i, 4); return v; }

__device__ __forceinline__ h2 readlane_h2(h2 v, int l) {
    return i_to_h2(__builtin_amdgcn_readlane(h2_to_i(v), l));
}
__device__ __forceinline__ h2 bperm_h2(int byte_addr, h2 v) {
    return i_to_h2(__builtin_amdgcn_ds_bpermute(byte_addr, h2_to_i(v)));
}
template <int CTRL>
__device__ __forceinline__ h2 dpp_h2(h2 v) {
    return i_to_h2(__builtin_amdgcn_update_dpp(0, h2_to_i(v), CTRL, 0xF, 0xF, true));
}

#if __has_builtin(__builtin_amdgcn_permlane16_swap) && __has_builtin(__builtin_amdgcn_permlane32_swap)
#define HAVE_PERMLANE_SWAP 1
#else
#define HAVE_PERMLANE_SWAP 0
#endif

// xor-exchange across lanes; M compile-time -> branches fold. DS bpermute
// for 16/32: overlapped under VALU work in the gate loop (R18 post-mortem).
__device__ __forceinline__ h2 xor_lane(h2 v, int M, int a16, int a32) {
    switch (M) {
    case 1:  return dpp_h2<0xB1>(v);               // quad_perm [1,0,3,2]
    case 2:  return dpp_h2<0x4E>(v);               // quad_perm [2,3,0,1]
    case 8:  return dpp_h2<0x128>(v);              // row_ror:8 == lane^8
    case 4:  return dpp_h2<0x141>(dpp_h2<0x1B>(v)); // xor3 ∘ xor7 = xor4
    case 16: return bperm_h2(a16, v);
    default: return bperm_h2(a32, v);              // 32
    }
}

// Epilogue folds: z + z[lane^M] via permlane-swap (VALU) — tail is
// latency-exposed, permlane (~4cy) beats a DS round-trip (~30cy).
// ret0 + ret1 == v[lane&~M] + v[lane|M] regardless of half convention.
__device__ __forceinline__ float fold16_f(float z, int a16) {
#if HAVE_PERMLANE_SWAP
    u2 r = __builtin_amdgcn_permlane16_swap(
        __float_as_uint(z), __float_as_uint(z), false, false);
    return __uint_as_float(r[0]) + __uint_as_float(r[1]);
#else
    return z + __int_as_float(__builtin_amdgcn_ds_bpermute(a16, __float_as_int(z)));
#endif
}
__device__ __forceinline__ float fold32_f(float z, int a32) {
#if HAVE_PERMLANE_SWAP
    u2 r = __builtin_amdgcn_permlane32_swap(
        __float_as_uint(z), __float_as_uint(z), false, false);
    return __uint_as_float(r[0]) + __uint_as_float(r[1]);
#else
    return z + __int_as_float(__builtin_amdgcn_ds_bpermute(a32, __float_as_int(z)));
#endif
}

__device__ __forceinline__ h2 mk_h2(float a, float b) {
    h2 r; r.x = (_Float16)a; r.y = (_Float16)b; return r;
}
__device__ __forceinline__ h2 xor_h2(h2 v, int m) {
    return i_to_h2(h2_to_i(v) ^ m);
}

__global__ __launch_bounds__(256, 4) void qsim_kernel(
    const float* __restrict__ x,       // (B, 10)
    const float* __restrict__ isc,     // (5, 20)
    const float* __restrict__ w,       // (5, 20)
    const float* __restrict__ oscale,  // (4)
    float* __restrict__ out,           // (B, 4)
    int B)
{
    const int lane = threadIdx.x & 63;
    const int wid  = (blockIdx.x * blockDim.x + threadIdx.x) >> 6;
    if (wid >= B) return;

    // ---- lane-parallel gate-coefficient computation (gates 0..49), fp32 ----
    // Each lane owns one gate; also pre-packs the h2 constants ONCE so the
    // gate loop needs only 4 readlanes per gate (no per-gate cvt/pack).
    float cUR, cUI, cVR, cVI;
    h2 pkUU, pkUI, pkVV, pkVI;
    {
        const int g   = (lane < 50) ? lane : 49;
        const int q   = g % 10;
        const int lyr = g / 10;
        const float xq    = x[wid * OBS + q];
        const float alpha = isc[lyr * 2 * NQ + q]      * xq;
        const float beta  = isc[lyr * 2 * NQ + NQ + q] * xq;
        const float gamma = w[lyr * 2 * NQ + q];
        const float delta = w[lyr * 2 * NQ + NQ + q];
        float sa, ca, sp, cp, sd, cd;
        __sincosf(0.5f * alpha,          &sa, &ca);
        __sincosf(0.5f * (beta + gamma), &sp, &cp);
        __sincosf(0.5f * delta,          &sd, &cd);
        const float A = cd * ca, Bt = sd * sa;
        const float C = cd * sa, D  = sd * ca;
        cUR = (A - Bt) * cp;
        cUI = -(A + Bt) * sp;
        cVR = (C + D) * cp;
        cVI = (C - D) * sp;
        pkUU = mk_h2(cUR,  cUR);    // (u, u)        real part broadcast
        pkUI = mk_h2(-cUI, cUI);    // (-ui, ui)
        pkVV = mk_h2(cVR,  cVR);    // (vr, vr)
        pkVI = mk_h2(-cVI, cVI);    // (-vi, vi)
    }

    // hoisted bperm byte-addresses (gates + ring)
    const int a16 = (lane ^ 16) * 4;
    const int a32 = (lane ^ 32) * 4;
    const int cnot_src  = (lane ^ (lane >> 1));
    const int addr_even = cnot_src * 4;            // r bit0 == 0
    const int addr_odd  = (cnot_src ^ 32) * 4;     // r bit0 == 1 (CNOT(3,4))

    // hoisted per-lane sign masks for lane-bit gates:
    // smP[q-4] = (lane has bit M set) ? 0x80008000 : 0  (kPI = kUI ^ smP,
    // kQR = (-kVV) ^ smP) — computed once, reused across 4 layers.
    int smP[6];
#pragma unroll
    for (int qq = 0; qq < 6; ++qq) {
        const int M = 1 << (5 - qq);               // q=4..9 -> M=32..1
        smP[qq] = (lane & M) ? (int)0x80008000 : 0;
    }

    h2 c[16];

    // ===== layer 0: direct product-state construction (fp32 -> f16x2) =====
    // amp(s) = prod_q (bit_q(s) ? v_q : u_q), gate column (u,v)=U|0>.
    {
        float Lr = 1.f, Li = 0.f;
#pragma unroll
        for (int q = 4; q < 10; ++q) {
            const float ur = readlane_f(cUR, q), ui = readlane_f(cUI, q);
            const float vr = readlane_f(cVR, q), vi = readlane_f(cVI, q);
            const int M = 1 << (9 - q);
            const float fr = (lane & M) ? vr : ur;
            const float fi = (lane & M) ? vi : ui;
            const float nr = Lr * fr - Li * fi;
            const float ni = Lr * fi + Li * fr;
            Lr = nr; Li = ni;
        }
        f2 cf[16];
        cf[0] = (f2){Lr, Li};
#pragma unroll
        for (int r = 1; r < 16; ++r) cf[r] = (f2){0.f, 0.f};
#pragma unroll
        for (int q = 3; q >= 0; --q) {
            const int m = 1 << (3 - q);
            const float ur = readlane_f(cUR, q), ui = readlane_f(cUI, q);
            const float vr = readlane_f(cVR, q), vi = readlane_f(cVI, q);
#pragma unroll
            for (int r0 = 0; r0 < 16; ++r0) {
                if (r0 >= m) continue;
                const f2 s = cf[r0];
                cf[r0 | m] = (f2){ s.x*vr - s.y*vi, s.x*vi + s.y*vr };
                cf[r0]     = (f2){ s.x*ur - s.y*ui, s.x*ui + s.y*ur };
            }
        }
#pragma unroll
        for (int r = 0; r < 16; ++r) c[r] = mk_h2(cf[r].x, cf[r].y);
    }

#define SWAPR(i, j) { h2 _t = c[i]; c[i] = c[j]; c[j] = _t; }

    for (int layer = 0; layer < NL; ++layer) {
        const int base = layer * NQ;   // wave-uniform

        // ---- fused single-qubit unitaries (layer 0 done by construction) ----
        if (layer > 0) {
#pragma unroll
            for (int q = 0; q < NQ; ++q) {
                // 4 readlanes of pre-packed constants -> wave-uniform SGPRs,
                // used directly as v_pk_fma_f16 operands (1 SGPR per instr).
                const h2 kUU = readlane_h2(pkUU, base + q);
                const h2 kUI = readlane_h2(pkUI, base + q);
                const h2 kVV = readlane_h2(pkVV, base + q);
                const h2 kVI = readlane_h2(pkVI, base + q);

                if (q < 4) {
                    // register-bit qubit: pair stride m inside the lane.
                    // c[r0] = u*c0 - conj(v)*c1 ; c[r1] = v*c0 + conj(u)*c1
                    // negations fold into pk_fma neg_lo/neg_hi modifiers.
                    const int m = 1 << (3 - q);
#pragma unroll
                    for (int r0 = 0; r0 < 16; ++r0) {
                        if (r0 & m) continue;
                        const int r1 = r0 | m;
                        const h2 c0 = c[r0], c1 = c[r1];
                        const h2 c0s = c0.yx, c1s = c1.yx;
                        c[r0] = kUU*c0 + kUI*c0s - kVV*c1 + kVI*c1s;
                        c[r1] = kVV*c0 + kVI*c0s + kUU*c1 - kUI*c1s;
                    }
                } else {
                    // lane-bit qubit: butterfly exchange with lane^M.
                    // per-lane signed constants via 2 xors with hoisted mask.
                    const int  M  = 1 << (9 - q);
                    const int  sm = smP[q - 4];
                    const h2 kPI = xor_h2(kUI, sm);          // bit? -kUI : kUI
                    const h2 kQR = xor_h2(-kVV, sm);         // bit?  kVV : -kVV
#pragma unroll
                    for (int r = 0; r < 16; ++r) {
                        const h2 mv = c[r];
                        const h2 pv = xor_lane(mv, M, a16, a32);
                        c[r] = kUU*mv + kPI*mv.yx + kQR*pv + kVI*pv.yx;
                    }
                }
            }
        }

        // ---- CNOT ring (skipped on last layer; folded into epilogue) ----
        if (layer < NL - 1) {
            // CNOT(0,1): ctrl r-bit3, tgt r-bit2 -> register swap
            SWAPR(8, 12) SWAPR(9, 13) SWAPR(10, 14) SWAPR(11, 15)
            // CNOT(1,2): ctrl r-bit2, tgt r-bit1
            SWAPR(4, 6)  SWAPR(5, 7)  SWAPR(12, 14) SWAPR(13, 15)
            // CNOT(2,3): ctrl r-bit1, tgt r-bit0
            SWAPR(2, 3)  SWAPR(6, 7)  SWAPR(10, 11) SWAPR(14, 15)
            // CNOT(3,4)..(8,9) fused: ONE bpermute per amplitude (f16x2).
            // lane^(lane>>1) is a general permutation — stays on DS.
#pragma unroll
            for (int r = 0; r < 16; ++r) {
                const int addr = (r & 1) ? addr_odd : addr_even;
                c[r] = bperm_h2(addr, c[r]);
            }
            // CNOT(9,0): ctrl lane-bit0, tgt r-bit3 -> cond register swap
            const bool ctl = (lane & 1) != 0;
#pragma unroll
            for (int r = 0; r < 8; ++r) {
                const h2 t0 = c[r], t1 = c[r + 8];
                c[r]     = ctl ? t1 : t0;
                c[r + 8] = ctl ? t0 : t1;
            }
        }
    }

    // ---- epilogue (fp32): <Z_i> after the (virtual) final ring ----
    // (Cb)_0 = q1+..+q9 -> reg bits r2,r1,r0 + all 6 lane bits
    // (Cb)_1 = q0+q1 -> r3,r2 ; (Cb)_2 -> r3,r2,r1 ; (Cb)_3 -> r3..r0
    const float sL = (__popc(lane) & 1) ? -1.f : 1.f;
    float z0 = 0.f, z1 = 0.f, z2 = 0.f, z3 = 0.f;
#pragma unroll
    for (int r = 0; r < 16; ++r) {
#if __has_builtin(__builtin_amdgcn_fdot2)
        const float pv = __builtin_amdgcn_fdot2(c[r], c[r], 0.0f, false);
#else
        const float cr = (float)c[r].x, ci = (float)c[r].y;
        const float pv = cr * cr + ci * ci;
#endif
        const float pvl = sL * pv;
        z0 += (__popc(r & 7)  & 1) ? -pvl : pvl;   // runtime sign via sL only
        z1 += (__popc(r & 12) & 1) ? -pv  : pv;    // compile-time signs
        z2 += (__popc(r & 14) & 1) ? -pv  : pv;
        z3 += (__popc(r & 15) & 1) ? -pv  : pv;
    }
    // f32 xor-lane reduction (DPP for 1,2,4,8; permlane-swap folds for 16,32)
#pragma unroll
    for (int m = 1; m < 64; m <<= 1) {
        if (m == 1)      { z0 += __int_as_float(__builtin_amdgcn_update_dpp(0, __float_as_int(z0), 0xB1, 0xF, 0xF, true));
                           z1 += __int_as_float(__builtin_amdgcn_update_dpp(0, __float_as_int(z1), 0xB1, 0xF, 0xF, true));
                           z2 += __int_as_float(__builtin_amdgcn_update_dpp(0, __float_as_int(z2), 0xB1, 0xF, 0xF, true));
                           z3 += __int_as_float(__builtin_amdgcn_update_dpp(0, __float_as_int(z3), 0xB1, 0xF, 0xF, true)); }
        else if (m == 2) { z0 += __int_as_float(__builtin_amdgcn_update_dpp(0, __float_as_int(z0), 0x4E, 0xF, 0xF, true));
                           z1 += __int_as_float(__builtin_amdgcn_update_dpp(0, __float_as_int(z1), 0x4E, 0xF, 0xF, true));
                           z2 += __int_as_float(__builtin_amdgcn_update_dpp(0, __float_as_int(z2), 0x4E, 0xF, 0xF, true));
                           z3 += __int_as_float(__builtin_amdgcn_update_dpp(0, __float_as_int(z3), 0x4E, 0xF, 0xF, true)); }
        else if (m == 4) { z0 += __int_as_float(__builtin_amdgcn_update_dpp(0, __builtin_amdgcn_update_dpp(0, __float_as_int(z0), 0x1B, 0xF, 0xF, true), 0x141, 0xF, 0xF, true));
                           z1 += __int_as_float(__builtin_amdgcn_update_dpp(0, __builtin_amdgcn_update_dpp(0, __float_as_int(z1), 0x1B, 0xF, 0xF, true), 0x141, 0xF, 0xF, true));
                           z2 += __int_as_float(__builtin_amdgcn_update_dpp(0, __builtin_amdgcn_update_dpp(0, __float_as_int(z2), 0x1B, 0xF, 0xF, true), 0x141, 0xF, 0xF, true));
                           z3 += __int_as_float(__builtin_amdgcn_update_dpp(0, __builtin_amdgcn_update_dpp(0, __float_as_int(z3), 0x1B, 0xF, 0xF, true), 0x141, 0xF, 0xF, true)); }
        else if (m == 8) { z0 += __int_as_float(__builtin_amdgcn_update_dpp(0, __float_as_int(z0), 0x128, 0xF, 0xF, true));
                           z1 += __int_as_float(__builtin_amdgcn_update_dpp(0, __float_as_int(z1), 0x128, 0xF, 0xF, true));
                           z2 += __int_as_float(__builtin_amdgcn_update_dpp(0, __float_as_int(z2), 0x128, 0xF, 0xF, true));
                           z3 += __int_as_float(__builtin_amdgcn_update_dpp(0, __float_as_int(z3), 0x128, 0xF, 0xF, true)); }
        else if (m == 16){ z0 = fold16_f(z0, a16);
                           z1 = fold16_f(z1, a16);
                           z2 = fold16_f(z2, a16);
                           z3 = fold16_f(z3, a16); }
        else             { z0 = fold32_f(z0, a32);
                           z1 = fold32_f(z1, a32);
                           z2 = fold32_f(z2, a32);
                           z3 = fold32_f(z3, a32); }
    }
    if (lane == 0) {
        out[wid * 4 + 0] = z0 * oscale[0];
        out[wid * 4 + 1] = z1 * oscale[1];
        out[wid * 4 + 2] = z2 * oscale[2];
        out[wid * 4 + 3] = z3 * oscale[3];
    }
#undef SWAPR
}

extern "C" void kernel_launch(void* const* d_in, const int* in_sizes, int n_in,
                              void* d_out, int out_size, void* d_ws, size_t ws_size,
                              hipStream_t stream) {
    const float* x      = (const float*)d_in[0];
    const float* isc    = (const float*)d_in[1];
    const float* w      = (const float*)d_in[2];
    const float* oscale = (const float*)d_in[3];
    float* out = (float*)d_out;

    const int B = in_sizes[0] / OBS;             // 4096
    const int threads = 256;                     // 4 waves -> 4 samples per block
    const int blocks = (B * 64 + threads - 1) / threads;
    qsim_kernel<<<blocks, threads, 0, stream>>>(x, isc, w, oscale, out, B);
}

// Round 3
// 86.331 us; speedup vs baseline: 1.0613x; 1.0164x over previous
//
#include <hip/hip_runtime.h>

// Batched 10-qubit statevector simulator — one 64-lane wave per sample.
// State: 1024 complex amps; s = (r<<6)|lane; qubit q <-> bit (9-q):
//   qubits 0..3 -> register-index bits (16 regs per lane)
//   qubits 4..9 -> lane bits (butterfly exchanges)
// R14 (38.5us): f16x2 state, v_pk_fma_f16 math, fp32 coeffs via readlane,
//   layer-0 product construction, ring-4 folded into epilogue parities.
// R18 POST-MORTEM (regressed): permlane in the GATE path moved 128 DS ops
//   onto the bottlenecked VALU pipe. Gate-loop DS ops are fully overlapped
//   (16 independent r-chains + 4 waves/SIMD). Lesson: on a VALU-issue-bound
//   kernel, never migrate overlapped DS work to VALU. permlane kept in the
//   epilogue folds only (latency-exposed tail).
// R19 (87.7us top-line, win): pre-packed h2 gate constants (4 readlanes/
//   gate), hoisted sign masks, v_dot2 epilogue — cut constant fabrication.
// R20 (this round): INVERSE of R18 — move the M=1/2/4/8 butterfly
//   exchanges OFF the VALU pipe. They were DPP ops = 320 VALU issue slots
//   per wave on the bottleneck pipe (M=4 was a 2-DPP chain). ds_swizzle_b32
//   BitMode (offset=(M<<10)|0x1F, xor within 32-halves — exact for M<32)
//   does each exchange as ONE DS op. DS pipe has headroom (22% busy; R11
//   staggering-null). Per gate, 2 pv-independent pk_fmas + 16 independent
//   r-chains cover the DS latency (same argument that makes the M=16/32
//   bperms free). Epilogue reduction keeps DPP (tail is latency-exposed).
//   Predict: VALU -320/wave, DS +256/wave, steady ~37 -> ~35.5-36us.
// Ladder: 137 (R0) -> 78 -> 64 -> 48 -> 44.8 -> 41.8 -> 38.5 (f16x2) ->
//   R19 const-fab cut.
// Falsified: extra waves/sample (R8), DS phase staggering (R11), ring
//   folding into gate coeffs (R12), rolled layer loop (R13), __hfma2 (R15),
//   op_sel asm + packed coeffs w/ asm (R16), 2 samples/wave (R17),
//   permlane in hot gate loop (R18: DS->VALU on issue-bound kernel).

constexpr int NQ  = 10;
constexpr int NL  = 5;
constexpr int OBS = 10;

typedef float        f2 __attribute__((ext_vector_type(2)));
typedef _Float16     h2 __attribute__((ext_vector_type(2)));
typedef unsigned int u2 __attribute__((ext_vector_type(2)));

__device__ __forceinline__ float readlane_f(float v, int l) {
    return __int_as_float(__builtin_amdgcn_readlane(__float_as_int(v), l));
}
__device__ __forceinline__ int h2_to_i(h2 v) { int i; __builtin_memcpy(&i, &v, 4); return i; }
__device__ __forceinline__ h2  i_to_h2(int i) { h2 v; __builtin_memcpy(&v, &i, 4); return v; }

__device__ __forceinline__ h2 readlane_h2(h2 v, int l) {
    return i_to_h2(__builtin_amdgcn_readlane(h2_to_i(v), l));
}
__device__ __forceinline__ h2 bperm_h2(int byte_addr, h2 v) {
    return i_to_h2(__builtin_amdgcn_ds_bpermute(byte_addr, h2_to_i(v)));
}
template <int CTRL>
__device__ __forceinline__ h2 dpp_h2(h2 v) {
    return i_to_h2(__builtin_amdgcn_update_dpp(0, h2_to_i(v), CTRL, 0xF, 0xF, true));
}
// ds_swizzle BitMode: offset = (xor<<10)|(or<<5)|and ; and=0x1F keeps all
// 5 lane bits, xor=M flips. Applies per 32-lane half -> exact for M<32.
template <int M>
__device__ __forceinline__ h2 swz_h2(h2 v) {
    return i_to_h2(__builtin_amdgcn_ds_swizzle(h2_to_i(v), (M << 10) | 0x1F));
}

#if __has_builtin(__builtin_amdgcn_permlane16_swap) && __has_builtin(__builtin_amdgcn_permlane32_swap)
#define HAVE_PERMLANE_SWAP 1
#else
#define HAVE_PERMLANE_SWAP 0
#endif

// xor-exchange across lanes; M compile-time -> branches fold.
// ALL gate-loop exchanges live on the DS pipe (overlapped region; VALU is
// the bottleneck pipe — R18/R20 pipe-balance lesson).
__device__ __forceinline__ h2 xor_lane(h2 v, int M, int a16, int a32) {
    switch (M) {
    case 1:  return swz_h2<1>(v);
    case 2:  return swz_h2<2>(v);
    case 4:  return swz_h2<4>(v);
    case 8:  return swz_h2<8>(v);
    case 16: return bperm_h2(a16, v);
    default: return bperm_h2(a32, v);              // 32
    }
}

// Epilogue folds: z + z[lane^M] via permlane-swap (VALU) — tail is
// latency-exposed, permlane (~4cy) beats a DS round-trip (~30cy).
// ret0 + ret1 == v[lane&~M] + v[lane|M] regardless of half convention.
__device__ __forceinline__ float fold16_f(float z, int a16) {
#if HAVE_PERMLANE_SWAP
    u2 r = __builtin_amdgcn_permlane16_swap(
        __float_as_uint(z), __float_as_uint(z), false, false);
    return __uint_as_float(r[0]) + __uint_as_float(r[1]);
#else
    return z + __int_as_float(__builtin_amdgcn_ds_bpermute(a16, __float_as_int(z)));
#endif
}
__device__ __forceinline__ float fold32_f(float z, int a32) {
#if HAVE_PERMLANE_SWAP
    u2 r = __builtin_amdgcn_permlane32_swap(
        __float_as_uint(z), __float_as_uint(z), false, false);
    return __uint_as_float(r[0]) + __uint_as_float(r[1]);
#else
    return z + __int_as_float(__builtin_amdgcn_ds_bpermute(a32, __float_as_int(z)));
#endif
}

__device__ __forceinline__ h2 mk_h2(float a, float b) {
    h2 r; r.x = (_Float16)a; r.y = (_Float16)b; return r;
}
__device__ __forceinline__ h2 xor_h2(h2 v, int m) {
    return i_to_h2(h2_to_i(v) ^ m);
}

__global__ __launch_bounds__(256, 4) void qsim_kernel(
    const float* __restrict__ x,       // (B, 10)
    const float* __restrict__ isc,     // (5, 20)
    const float* __restrict__ w,       // (5, 20)
    const float* __restrict__ oscale,  // (4)
    float* __restrict__ out,           // (B, 4)
    int B)
{
    const int lane = threadIdx.x & 63;
    const int wid  = (blockIdx.x * blockDim.x + threadIdx.x) >> 6;
    if (wid >= B) return;

    // ---- lane-parallel gate-coefficient computation (gates 0..49), fp32 ----
    // Each lane owns one gate; also pre-packs the h2 constants ONCE so the
    // gate loop needs only 4 readlanes per gate (no per-gate cvt/pack).
    float cUR, cUI, cVR, cVI;
    h2 pkUU, pkUI, pkVV, pkVI;
    {
        const int g   = (lane < 50) ? lane : 49;
        const int q   = g % 10;
        const int lyr = g / 10;
        const float xq    = x[wid * OBS + q];
        const float alpha = isc[lyr * 2 * NQ + q]      * xq;
        const float beta  = isc[lyr * 2 * NQ + NQ + q] * xq;
        const float gamma = w[lyr * 2 * NQ + q];
        const float delta = w[lyr * 2 * NQ + NQ + q];
        float sa, ca, sp, cp, sd, cd;
        __sincosf(0.5f * alpha,          &sa, &ca);
        __sincosf(0.5f * (beta + gamma), &sp, &cp);
        __sincosf(0.5f * delta,          &sd, &cd);
        const float A = cd * ca, Bt = sd * sa;
        const float C = cd * sa, D  = sd * ca;
        cUR = (A - Bt) * cp;
        cUI = -(A + Bt) * sp;
        cVR = (C + D) * cp;
        cVI = (C - D) * sp;
        pkUU = mk_h2(cUR,  cUR);    // (u, u)        real part broadcast
        pkUI = mk_h2(-cUI, cUI);    // (-ui, ui)
        pkVV = mk_h2(cVR,  cVR);    // (vr, vr)
        pkVI = mk_h2(-cVI, cVI);    // (-vi, vi)
    }

    // hoisted bperm byte-addresses (gates + ring)
    const int a16 = (lane ^ 16) * 4;
    const int a32 = (lane ^ 32) * 4;
    const int cnot_src  = (lane ^ (lane >> 1));
    const int addr_even = cnot_src * 4;            // r bit0 == 0
    const int addr_odd  = (cnot_src ^ 32) * 4;     // r bit0 == 1 (CNOT(3,4))

    // hoisted per-lane sign masks for lane-bit gates:
    // smP[q-4] = (lane has bit M set) ? 0x80008000 : 0  (kPI = kUI ^ smP,
    // kQR = (-kVV) ^ smP) — computed once, reused across 4 layers.
    int smP[6];
#pragma unroll
    for (int qq = 0; qq < 6; ++qq) {
        const int M = 1 << (5 - qq);               // q=4..9 -> M=32..1
        smP[qq] = (lane & M) ? (int)0x80008000 : 0;
    }

    h2 c[16];

    // ===== layer 0: direct product-state construction (fp32 -> f16x2) =====
    // amp(s) = prod_q (bit_q(s) ? v_q : u_q), gate column (u,v)=U|0>.
    {
        float Lr = 1.f, Li = 0.f;
#pragma unroll
        for (int q = 4; q < 10; ++q) {
            const float ur = readlane_f(cUR, q), ui = readlane_f(cUI, q);
            const float vr = readlane_f(cVR, q), vi = readlane_f(cVI, q);
            const int M = 1 << (9 - q);
            const float fr = (lane & M) ? vr : ur;
            const float fi = (lane & M) ? vi : ui;
            const float nr = Lr * fr - Li * fi;
            const float ni = Lr * fi + Li * fr;
            Lr = nr; Li = ni;
        }
        f2 cf[16];
        cf[0] = (f2){Lr, Li};
#pragma unroll
        for (int r = 1; r < 16; ++r) cf[r] = (f2){0.f, 0.f};
#pragma unroll
        for (int q = 3; q >= 0; --q) {
            const int m = 1 << (3 - q);
            const float ur = readlane_f(cUR, q), ui = readlane_f(cUI, q);
            const float vr = readlane_f(cVR, q), vi = readlane_f(cVI, q);
#pragma unroll
            for (int r0 = 0; r0 < 16; ++r0) {
                if (r0 >= m) continue;
                const f2 s = cf[r0];
                cf[r0 | m] = (f2){ s.x*vr - s.y*vi, s.x*vi + s.y*vr };
                cf[r0]     = (f2){ s.x*ur - s.y*ui, s.x*ui + s.y*ur };
            }
        }
#pragma unroll
        for (int r = 0; r < 16; ++r) c[r] = mk_h2(cf[r].x, cf[r].y);
    }

#define SWAPR(i, j) { h2 _t = c[i]; c[i] = c[j]; c[j] = _t; }

    for (int layer = 0; layer < NL; ++layer) {
        const int base = layer * NQ;   // wave-uniform

        // ---- fused single-qubit unitaries (layer 0 done by construction) ----
        if (layer > 0) {
#pragma unroll
            for (int q = 0; q < NQ; ++q) {
                // 4 readlanes of pre-packed constants -> wave-uniform SGPRs,
                // used directly as v_pk_fma_f16 operands (1 SGPR per instr).
                const h2 kUU = readlane_h2(pkUU, base + q);
                const h2 kUI = readlane_h2(pkUI, base + q);
                const h2 kVV = readlane_h2(pkVV, base + q);
                const h2 kVI = readlane_h2(pkVI, base + q);

                if (q < 4) {
                    // register-bit qubit: pair stride m inside the lane.
                    // c[r0] = u*c0 - conj(v)*c1 ; c[r1] = v*c0 + conj(u)*c1
                    // negations fold into pk_fma neg_lo/neg_hi modifiers.
                    const int m = 1 << (3 - q);
#pragma unroll
                    for (int r0 = 0; r0 < 16; ++r0) {
                        if (r0 & m) continue;
                        const int r1 = r0 | m;
                        const h2 c0 = c[r0], c1 = c[r1];
                        const h2 c0s = c0.yx, c1s = c1.yx;
                        c[r0] = kUU*c0 + kUI*c0s - kVV*c1 + kVI*c1s;
                        c[r1] = kVV*c0 + kVI*c0s + kUU*c1 - kUI*c1s;
                    }
                } else {
                    // lane-bit qubit: butterfly exchange with lane^M (DS pipe).
                    // per-lane signed constants via 2 xors with hoisted mask.
                    const int  M  = 1 << (9 - q);
                    const int  sm = smP[q - 4];
                    const h2 kPI = xor_h2(kUI, sm);          // bit? -kUI : kUI
                    const h2 kQR = xor_h2(-kVV, sm);         // bit?  kVV : -kVV
#pragma unroll
                    for (int r = 0; r < 16; ++r) {
                        const h2 mv = c[r];
                        const h2 pv = xor_lane(mv, M, a16, a32);
                        c[r] = kUU*mv + kPI*mv.yx + kQR*pv + kVI*pv.yx;
                    }
                }
            }
        }

        // ---- CNOT ring (skipped on last layer; folded into epilogue) ----
        if (layer < NL - 1) {
            // CNOT(0,1): ctrl r-bit3, tgt r-bit2 -> register swap
            SWAPR(8, 12) SWAPR(9, 13) SWAPR(10, 14) SWAPR(11, 15)
            // CNOT(1,2): ctrl r-bit2, tgt r-bit1
            SWAPR(4, 6)  SWAPR(5, 7)  SWAPR(12, 14) SWAPR(13, 15)
            // CNOT(2,3): ctrl r-bit1, tgt r-bit0
            SWAPR(2, 3)  SWAPR(6, 7)  SWAPR(10, 11) SWAPR(14, 15)
            // CNOT(3,4)..(8,9) fused: ONE bpermute per amplitude (f16x2).
            // lane^(lane>>1) is a general permutation — stays on DS.
#pragma unroll
            for (int r = 0; r < 16; ++r) {
                const int addr = (r & 1) ? addr_odd : addr_even;
                c[r] = bperm_h2(addr, c[r]);
            }
            // CNOT(9,0): ctrl lane-bit0, tgt r-bit3 -> cond register swap
            const bool ctl = (lane & 1) != 0;
#pragma unroll
            for (int r = 0; r < 8; ++r) {
                const h2 t0 = c[r], t1 = c[r + 8];
                c[r]     = ctl ? t1 : t0;
                c[r + 8] = ctl ? t0 : t1;
            }
        }
    }

    // ---- epilogue (fp32): <Z_i> after the (virtual) final ring ----
    // (Cb)_0 = q1+..+q9 -> reg bits r2,r1,r0 + all 6 lane bits
    // (Cb)_1 = q0+q1 -> r3,r2 ; (Cb)_2 -> r3,r2,r1 ; (Cb)_3 -> r3..r0
    const float sL = (__popc(lane) & 1) ? -1.f : 1.f;
    float z0 = 0.f, z1 = 0.f, z2 = 0.f, z3 = 0.f;
#pragma unroll
    for (int r = 0; r < 16; ++r) {
#if __has_builtin(__builtin_amdgcn_fdot2)
        const float pv = __builtin_amdgcn_fdot2(c[r], c[r], 0.0f, false);
#else
        const float cr = (float)c[r].x, ci = (float)c[r].y;
        const float pv = cr * cr + ci * ci;
#endif
        const float pvl = sL * pv;
        z0 += (__popc(r & 7)  & 1) ? -pvl : pvl;   // runtime sign via sL only
        z1 += (__popc(r & 12) & 1) ? -pv  : pv;    // compile-time signs
        z2 += (__popc(r & 14) & 1) ? -pv  : pv;
        z3 += (__popc(r & 15) & 1) ? -pv  : pv;
    }
    // f32 xor-lane reduction (DPP for 1,2,4,8; permlane-swap folds for 16,32)
#pragma unroll
    for (int m = 1; m < 64; m <<= 1) {
        if (m == 1)      { z0 += __int_as_float(__builtin_amdgcn_update_dpp(0, __float_as_int(z0), 0xB1, 0xF, 0xF, true));
                           z1 += __int_as_float(__builtin_amdgcn_update_dpp(0, __float_as_int(z1), 0xB1, 0xF, 0xF, true));
                           z2 += __int_as_float(__builtin_amdgcn_update_dpp(0, __float_as_int(z2), 0xB1, 0xF, 0xF, true));
                           z3 += __int_as_float(__builtin_amdgcn_update_dpp(0, __float_as_int(z3), 0xB1, 0xF, 0xF, true)); }
        else if (m == 2) { z0 += __int_as_float(__builtin_amdgcn_update_dpp(0, __float_as_int(z0), 0x4E, 0xF, 0xF, true));
                           z1 += __int_as_float(__builtin_amdgcn_update_dpp(0, __float_as_int(z1), 0x4E, 0xF, 0xF, true));
                           z2 += __int_as_float(__builtin_amdgcn_update_dpp(0, __float_as_int(z2), 0x4E, 0xF, 0xF, true));
                           z3 += __int_as_float(__builtin_amdgcn_update_dpp(0, __float_as_int(z3), 0x4E, 0xF, 0xF, true)); }
        else if (m == 4) { z0 += __int_as_float(__builtin_amdgcn_update_dpp(0, __builtin_amdgcn_update_dpp(0, __float_as_int(z0), 0x1B, 0xF, 0xF, true), 0x141, 0xF, 0xF, true));
                           z1 += __int_as_float(__builtin_amdgcn_update_dpp(0, __builtin_amdgcn_update_dpp(0, __float_as_int(z1), 0x1B, 0xF, 0xF, true), 0x141, 0xF, 0xF, true));
                           z2 += __int_as_float(__builtin_amdgcn_update_dpp(0, __builtin_amdgcn_update_dpp(0, __float_as_int(z2), 0x1B, 0xF, 0xF, true), 0x141, 0xF, 0xF, true));
                           z3 += __int_as_float(__builtin_amdgcn_update_dpp(0, __builtin_amdgcn_update_dpp(0, __float_as_int(z3), 0x1B, 0xF, 0xF, true), 0x141, 0xF, 0xF, true)); }
        else if (m == 8) { z0 += __int_as_float(__builtin_amdgcn_update_dpp(0, __float_as_int(z0), 0x128, 0xF, 0xF, true));
                           z1 += __int_as_float(__builtin_amdgcn_update_dpp(0, __float_as_int(z1), 0x128, 0xF, 0xF, true));
                           z2 += __int_as_float(__builtin_amdgcn_update_dpp(0, __float_as_int(z2), 0x128, 0xF, 0xF, true));
                           z3 += __int_as_float(__builtin_amdgcn_update_dpp(0, __float_as_int(z3), 0x128, 0xF, 0xF, true)); }
        else if (m == 16){ z0 = fold16_f(z0, a16);
                           z1 = fold16_f(z1, a16);
                           z2 = fold16_f(z2, a16);
                           z3 = fold16_f(z3, a16); }
        else             { z0 = fold32_f(z0, a32);
                           z1 = fold32_f(z1, a32);
                           z2 = fold32_f(z2, a32);
                           z3 = fold32_f(z3, a32); }
    }
    if (lane == 0) {
        out[wid * 4 + 0] = z0 * oscale[0];
        out[wid * 4 + 1] = z1 * oscale[1];
        out[wid * 4 + 2] = z2 * oscale[2];
        out[wid * 4 + 3] = z3 * oscale[3];
    }
#undef SWAPR
}

extern "C" void kernel_launch(void* const* d_in, const int* in_sizes, int n_in,
                              void* d_out, int out_size, void* d_ws, size_t ws_size,
                              hipStream_t stream) {
    const float* x      = (const float*)d_in[0];
    const float* isc    = (const float*)d_in[1];
    const float* w      = (const float*)d_in[2];
    const float* oscale = (const float*)d_in[3];
    float* out = (float*)d_out;

    const int B = in_sizes[0] / OBS;             // 4096
    const int threads = 256;                     // 4 waves -> 4 samples per block
    const int blocks = (B * 64 + threads - 1) / threads;
    qsim_kernel<<<blocks, threads, 0, stream>>>(x, isc, w, oscale, out, B);
}

// Round 4
// 84.676 us; speedup vs baseline: 1.0821x; 1.0196x over previous
//
#include <hip/hip_runtime.h>

// Batched 10-qubit statevector simulator — one 64-lane wave per sample.
// State: 1024 complex amps; s = (r<<6)|lane; qubit q <-> bit (9-q):
//   qubits 0..3 -> register-index bits (16 regs per lane)
//   qubits 4..9 -> lane bits (butterfly exchanges)
// R14 (38.5us): f16x2 state, v_pk_fma_f16 math, fp32 coeffs via readlane,
//   layer-0 product construction, ring-4 folded into epilogue parities.
// R18 POST-MORTEM (regressed): permlane in the GATE path moved 128 DS ops
//   onto the bottlenecked VALU pipe. Lesson: on a VALU-issue-bound kernel,
//   never migrate overlapped DS work to VALU; permlane only in the
//   latency-exposed epilogue tail.
// R19 (87.7 top-line, win): pre-packed h2 gate constants + hoisted sign
//   masks + v_dot2 epilogue — cut constant fabrication.
// R20 (86.3 top-line, win): M=1/2/4/8 exchanges DPP -> ds_swizzle_b32
//   (BitMode (M<<10)|0x1F): -320 VALU issue slots moved to DS pipe which
//   has headroom. Both directions of the pipe-balance law now confirmed.
// R21 (this round): two more VALU-issue cuts, zero data-path change.
//   (a) gate-constant broadcast via LDS: prologue ds_write_b128 of the 4
//       packed h2 constants per gate (lanes 0..49, wave-private slab, no
//       barrier needed — same-wave producer/consumer); each layer does 10
//       wave-uniform ds_read_b128 (uniform addr = broadcast, conflict-
//       free). Replaces 160 v_readlane (VALU slots + VALU->SALU hazards)
//       with 40 DS ops. pk_fma now takes all-VGPR operands.
//   (b) epilogue: factor sL out of z0 (sL=+-1, exact) -> kills 16 muls;
//       pack z0..z3 as two f2 accumulators -> v_pk_add_f32 with
//       compile-time neg_lo/neg_hi signs: 6 ops/r -> 3 ops/r.
//   Predict: ~-205 VALU slots/wave, +40 DS; steady 36.3 -> ~35.5us.
// Ladder: 137 (R0) -> 78 -> 64 -> 48 -> 44.8 -> 41.8 -> 38.5 (f16x2) ->
//   R19 const-fab cut -> R20 swizzle migration (steady ~36.3).
// Falsified: extra waves/sample (R8), DS phase staggering (R11), ring
//   folding into gate coeffs (R12), rolled layer loop (R13), __hfma2 (R15),
//   op_sel asm + packed coeffs w/ asm (R16), 2 samples/wave (R17),
//   permlane in hot gate loop (R18: DS->VALU on issue-bound kernel).

constexpr int NQ  = 10;
constexpr int NL  = 5;
constexpr int OBS = 10;

typedef float        f2 __attribute__((ext_vector_type(2)));
typedef _Float16     h2 __attribute__((ext_vector_type(2)));
typedef unsigned int u2 __attribute__((ext_vector_type(2)));
typedef int          i4 __attribute__((ext_vector_type(4)));

__device__ __forceinline__ float readlane_f(float v, int l) {
    return __int_as_float(__builtin_amdgcn_readlane(__float_as_int(v), l));
}
__device__ __forceinline__ int h2_to_i(h2 v) { int i; __builtin_memcpy(&i, &v, 4); return i; }
__device__ __forceinline__ h2  i_to_h2(int i) { h2 v; __builtin_memcpy(&v, &i, 4); return v; }

__device__ __forceinline__ h2 bperm_h2(int byte_addr, h2 v) {
    return i_to_h2(__builtin_amdgcn_ds_bpermute(byte_addr, h2_to_i(v)));
}
template <int CTRL>
__device__ __forceinline__ h2 dpp_h2(h2 v) {
    return i_to_h2(__builtin_amdgcn_update_dpp(0, h2_to_i(v), CTRL, 0xF, 0xF, true));
}
// ds_swizzle BitMode: offset = (xor<<10)|(or<<5)|and ; and=0x1F keeps all
// 5 lane bits, xor=M flips. Applies per 32-lane half -> exact for M<32.
template <int M>
__device__ __forceinline__ h2 swz_h2(h2 v) {
    return i_to_h2(__builtin_amdgcn_ds_swizzle(h2_to_i(v), (M << 10) | 0x1F));
}

#if __has_builtin(__builtin_amdgcn_permlane16_swap) && __has_builtin(__builtin_amdgcn_permlane32_swap)
#define HAVE_PERMLANE_SWAP 1
#else
#define HAVE_PERMLANE_SWAP 0
#endif

// xor-exchange across lanes; M compile-time -> branches fold.
// ALL gate-loop exchanges live on the DS pipe (overlapped region; VALU is
// the bottleneck pipe — R18/R20 pipe-balance lesson).
__device__ __forceinline__ h2 xor_lane(h2 v, int M, int a16, int a32) {
    switch (M) {
    case 1:  return swz_h2<1>(v);
    case 2:  return swz_h2<2>(v);
    case 4:  return swz_h2<4>(v);
    case 8:  return swz_h2<8>(v);
    case 16: return bperm_h2(a16, v);
    default: return bperm_h2(a32, v);              // 32
    }
}

// Epilogue folds: z + z[lane^M] via permlane-swap (VALU) — tail is
// latency-exposed, permlane (~4cy) beats a DS round-trip (~30cy).
// ret0 + ret1 == v[lane&~M] + v[lane|M] regardless of half convention.
__device__ __forceinline__ float fold16_f(float z, int a16) {
#if HAVE_PERMLANE_SWAP
    u2 r = __builtin_amdgcn_permlane16_swap(
        __float_as_uint(z), __float_as_uint(z), false, false);
    return __uint_as_float(r[0]) + __uint_as_float(r[1]);
#else
    return z + __int_as_float(__builtin_amdgcn_ds_bpermute(a16, __float_as_int(z)));
#endif
}
__device__ __forceinline__ float fold32_f(float z, int a32) {
#if HAVE_PERMLANE_SWAP
    u2 r = __builtin_amdgcn_permlane32_swap(
        __float_as_uint(z), __float_as_uint(z), false, false);
    return __uint_as_float(r[0]) + __uint_as_float(r[1]);
#else
    return z + __int_as_float(__builtin_amdgcn_ds_bpermute(a32, __float_as_int(z)));
#endif
}

__device__ __forceinline__ h2 mk_h2(float a, float b) {
    h2 r; r.x = (_Float16)a; r.y = (_Float16)b; return r;
}
__device__ __forceinline__ h2 xor_h2(h2 v, int m) {
    return i_to_h2(h2_to_i(v) ^ m);
}

__global__ __launch_bounds__(256, 4) void qsim_kernel(
    const float* __restrict__ x,       // (B, 10)
    const float* __restrict__ isc,     // (5, 20)
    const float* __restrict__ w,       // (5, 20)
    const float* __restrict__ oscale,  // (4)
    float* __restrict__ out,           // (B, 4)
    int B)
{
    const int lane  = threadIdx.x & 63;
    const int wslot = threadIdx.x >> 6;            // wave index within block
    const int wid   = (blockIdx.x * blockDim.x + threadIdx.x) >> 6;
    if (wid >= B) return;

    // per-wave constant slab: 50 gates x 4 dwords (pkUU,pkUI,pkVV,pkVI)
    __shared__ int ldsK[4][50 * 4];

    // ---- lane-parallel gate-coefficient computation (gates 0..49), fp32 ----
    // Each lane owns one gate; packs the 4 h2 constants and stores them to
    // the wave-private LDS slab with ONE ds_write_b128. No barrier: the
    // only consumer is this same wave (same-wave DS ordering via lgkmcnt).
    float cUR, cUI, cVR, cVI;
    {
        const int g   = (lane < 50) ? lane : 49;
        const int q   = g % 10;
        const int lyr = g / 10;
        const float xq    = x[wid * OBS + q];
        const float alpha = isc[lyr * 2 * NQ + q]      * xq;
        const float beta  = isc[lyr * 2 * NQ + NQ + q] * xq;
        const float gamma = w[lyr * 2 * NQ + q];
        const float delta = w[lyr * 2 * NQ + NQ + q];
        float sa, ca, sp, cp, sd, cd;
        __sincosf(0.5f * alpha,          &sa, &ca);
        __sincosf(0.5f * (beta + gamma), &sp, &cp);
        __sincosf(0.5f * delta,          &sd, &cd);
        const float A = cd * ca, Bt = sd * sa;
        const float C = cd * sa, D  = sd * ca;
        cUR = (A - Bt) * cp;
        cUI = -(A + Bt) * sp;
        cVR = (C + D) * cp;
        cVI = (C - D) * sp;
        if (lane < 50) {
            i4 pk;
            pk.x = h2_to_i(mk_h2(cUR,  cUR));      // kUU = (u, u)
            pk.y = h2_to_i(mk_h2(-cUI, cUI));      // kUI = (-ui, ui)
            pk.z = h2_to_i(mk_h2(cVR,  cVR));      // kVV = (vr, vr)
            pk.w = h2_to_i(mk_h2(-cVI, cVI));      // kVI = (-vi, vi)
            *reinterpret_cast<i4*>(&ldsK[wslot][lane * 4]) = pk;
        }
    }

    // hoisted bperm byte-addresses (gates + ring)
    const int a16 = (lane ^ 16) * 4;
    const int a32 = (lane ^ 32) * 4;
    const int cnot_src  = (lane ^ (lane >> 1));
    const int addr_even = cnot_src * 4;            // r bit0 == 0
    const int addr_odd  = (cnot_src ^ 32) * 4;     // r bit0 == 1 (CNOT(3,4))

    // hoisted per-lane sign masks for lane-bit gates:
    // smP[q-4] = (lane has bit M set) ? 0x80008000 : 0  (kPI = kUI ^ smP,
    // kQR = (-kVV) ^ smP) — computed once, reused across 4 layers.
    int smP[6];
#pragma unroll
    for (int qq = 0; qq < 6; ++qq) {
        const int M = 1 << (5 - qq);               // q=4..9 -> M=32..1
        smP[qq] = (lane & M) ? (int)0x80008000 : 0;
    }

    h2 c[16];

    // ===== layer 0: direct product-state construction (fp32 -> f16x2) =====
    // amp(s) = prod_q (bit_q(s) ? v_q : u_q), gate column (u,v)=U|0>.
    {
        float Lr = 1.f, Li = 0.f;
#pragma unroll
        for (int q = 4; q < 10; ++q) {
            const float ur = readlane_f(cUR, q), ui = readlane_f(cUI, q);
            const float vr = readlane_f(cVR, q), vi = readlane_f(cVI, q);
            const int M = 1 << (9 - q);
            const float fr = (lane & M) ? vr : ur;
            const float fi = (lane & M) ? vi : ui;
            const float nr = Lr * fr - Li * fi;
            const float ni = Lr * fi + Li * fr;
            Lr = nr; Li = ni;
        }
        f2 cf[16];
        cf[0] = (f2){Lr, Li};
#pragma unroll
        for (int r = 1; r < 16; ++r) cf[r] = (f2){0.f, 0.f};
#pragma unroll
        for (int q = 3; q >= 0; --q) {
            const int m = 1 << (3 - q);
            const float ur = readlane_f(cUR, q), ui = readlane_f(cUI, q);
            const float vr = readlane_f(cVR, q), vi = readlane_f(cVI, q);
#pragma unroll
            for (int r0 = 0; r0 < 16; ++r0) {
                if (r0 >= m) continue;
                const f2 s = cf[r0];
                cf[r0 | m] = (f2){ s.x*vr - s.y*vi, s.x*vi + s.y*vr };
                cf[r0]     = (f2){ s.x*ur - s.y*ui, s.x*ui + s.y*ur };
            }
        }
#pragma unroll
        for (int r = 0; r < 16; ++r) c[r] = mk_h2(cf[r].x, cf[r].y);
    }

#define SWAPR(i, j) { h2 _t = c[i]; c[i] = c[j]; c[j] = _t; }

    for (int layer = 0; layer < NL; ++layer) {
        const int base = layer * NQ;   // wave-uniform

        // ---- fused single-qubit unitaries (layer 0 done by construction) ----
        if (layer > 0) {
            // broadcast-load this layer's 10 gate-constant quads from the
            // wave-private LDS slab (wave-uniform addr -> conflict-free).
            h2 K[NQ][4];
#pragma unroll
            for (int q = 0; q < NQ; ++q) {
                const i4 pk = *reinterpret_cast<const i4*>(
                    &ldsK[wslot][(base + q) * 4]);
                K[q][0] = i_to_h2(pk.x);           // kUU
                K[q][1] = i_to_h2(pk.y);           // kUI
                K[q][2] = i_to_h2(pk.z);           // kVV
                K[q][3] = i_to_h2(pk.w);           // kVI
            }
#pragma unroll
            for (int q = 0; q < NQ; ++q) {
                const h2 kUU = K[q][0];
                const h2 kUI = K[q][1];
                const h2 kVV = K[q][2];
                const h2 kVI = K[q][3];

                if (q < 4) {
                    // register-bit qubit: pair stride m inside the lane.
                    // c[r0] = u*c0 - conj(v)*c1 ; c[r1] = v*c0 + conj(u)*c1
                    // negations fold into pk_fma neg_lo/neg_hi modifiers.
                    const int m = 1 << (3 - q);
#pragma unroll
                    for (int r0 = 0; r0 < 16; ++r0) {
                        if (r0 & m) continue;
                        const int r1 = r0 | m;
                        const h2 c0 = c[r0], c1 = c[r1];
                        const h2 c0s = c0.yx, c1s = c1.yx;
                        c[r0] = kUU*c0 + kUI*c0s - kVV*c1 + kVI*c1s;
                        c[r1] = kVV*c0 + kVI*c0s + kUU*c1 - kUI*c1s;
                    }
                } else {
                    // lane-bit qubit: butterfly exchange with lane^M (DS pipe).
                    // per-lane signed constants via 2 xors with hoisted mask.
                    const int  M  = 1 << (9 - q);
                    const int  sm = smP[q - 4];
                    const h2 kPI = xor_h2(kUI, sm);          // bit? -kUI : kUI
                    const h2 kQR = xor_h2(-kVV, sm);         // bit?  kVV : -kVV
#pragma unroll
                    for (int r = 0; r < 16; ++r) {
                        const h2 mv = c[r];
                        const h2 pv = xor_lane(mv, M, a16, a32);
                        c[r] = kUU*mv + kPI*mv.yx + kQR*pv + kVI*pv.yx;
                    }
                }
            }
        }

        // ---- CNOT ring (skipped on last layer; folded into epilogue) ----
        if (layer < NL - 1) {
            // CNOT(0,1): ctrl r-bit3, tgt r-bit2 -> register swap
            SWAPR(8, 12) SWAPR(9, 13) SWAPR(10, 14) SWAPR(11, 15)
            // CNOT(1,2): ctrl r-bit2, tgt r-bit1
            SWAPR(4, 6)  SWAPR(5, 7)  SWAPR(12, 14) SWAPR(13, 15)
            // CNOT(2,3): ctrl r-bit1, tgt r-bit0
            SWAPR(2, 3)  SWAPR(6, 7)  SWAPR(10, 11) SWAPR(14, 15)
            // CNOT(3,4)..(8,9) fused: ONE bpermute per amplitude (f16x2).
            // lane^(lane>>1) is a general permutation — stays on DS.
#pragma unroll
            for (int r = 0; r < 16; ++r) {
                const int addr = (r & 1) ? addr_odd : addr_even;
                c[r] = bperm_h2(addr, c[r]);
            }
            // CNOT(9,0): ctrl lane-bit0, tgt r-bit3 -> cond register swap
            const bool ctl = (lane & 1) != 0;
#pragma unroll
            for (int r = 0; r < 8; ++r) {
                const h2 t0 = c[r], t1 = c[r + 8];
                c[r]     = ctl ? t1 : t0;
                c[r + 8] = ctl ? t0 : t1;
            }
        }
    }

    // ---- epilogue (fp32): <Z_i> after the (virtual) final ring ----
    // (Cb)_0 = q1+..+q9 -> reg bits r2,r1,r0 + all 6 lane bits
    // (Cb)_1 = q0+q1 -> r3,r2 ; (Cb)_2 -> r3,r2,r1 ; (Cb)_3 -> r3..r0
    // sL (=+-1, lane parity) factored OUT of the z0 loop (exact); packed
    // f2 accumulators -> v_pk_add_f32 with compile-time neg modifiers.
    f2 Z01 = (f2){0.f, 0.f}, Z23 = (f2){0.f, 0.f};
#pragma unroll
    for (int r = 0; r < 16; ++r) {
#if __has_builtin(__builtin_amdgcn_fdot2)
        const float pv = __builtin_amdgcn_fdot2(c[r], c[r], 0.0f, false);
#else
        const float cr = (float)c[r].x, ci = (float)c[r].y;
        const float pv = cr * cr + ci * ci;
#endif
        Z01 += (f2){ (__popc(r & 7)  & 1) ? -pv : pv,
                     (__popc(r & 12) & 1) ? -pv : pv };
        Z23 += (f2){ (__popc(r & 14) & 1) ? -pv : pv,
                     (__popc(r & 15) & 1) ? -pv : pv };
    }
    const float sL = (__popc(lane) & 1) ? -1.f : 1.f;
    float z0 = Z01.x * sL, z1 = Z01.y, z2 = Z23.x, z3 = Z23.y;
    // f32 xor-lane reduction (DPP for 1,2,4,8; permlane-swap folds for 16,32)
#pragma unroll
    for (int m = 1; m < 64; m <<= 1) {
        if (m == 1)      { z0 += __int_as_float(__builtin_amdgcn_update_dpp(0, __float_as_int(z0), 0xB1, 0xF, 0xF, true));
                           z1 += __int_as_float(__builtin_amdgcn_update_dpp(0, __float_as_int(z1), 0xB1, 0xF, 0xF, true));
                           z2 += __int_as_float(__builtin_amdgcn_update_dpp(0, __float_as_int(z2), 0xB1, 0xF, 0xF, true));
                           z3 += __int_as_float(__builtin_amdgcn_update_dpp(0, __float_as_int(z3), 0xB1, 0xF, 0xF, true)); }
        else if (m == 2) { z0 += __int_as_float(__builtin_amdgcn_update_dpp(0, __float_as_int(z0), 0x4E, 0xF, 0xF, true));
                           z1 += __int_as_float(__builtin_amdgcn_update_dpp(0, __float_as_int(z1), 0x4E, 0xF, 0xF, true));
                           z2 += __int_as_float(__builtin_amdgcn_update_dpp(0, __float_as_int(z2), 0x4E, 0xF, 0xF, true));
                           z3 += __int_as_float(__builtin_amdgcn_update_dpp(0, __float_as_int(z3), 0x4E, 0xF, 0xF, true)); }
        else if (m == 4) { z0 += __int_as_float(__builtin_amdgcn_update_dpp(0, __builtin_amdgcn_update_dpp(0, __float_as_int(z0), 0x1B, 0xF, 0xF, true), 0x141, 0xF, 0xF, true));
                           z1 += __int_as_float(__builtin_amdgcn_update_dpp(0, __builtin_amdgcn_update_dpp(0, __float_as_int(z1), 0x1B, 0xF, 0xF, true), 0x141, 0xF, 0xF, true));
                           z2 += __int_as_float(__builtin_amdgcn_update_dpp(0, __builtin_amdgcn_update_dpp(0, __float_as_int(z2), 0x1B, 0xF, 0xF, true), 0x141, 0xF, 0xF, true));
                           z3 += __int_as_float(__builtin_amdgcn_update_dpp(0, __builtin_amdgcn_update_dpp(0, __float_as_int(z3), 0x1B, 0xF, 0xF, true), 0x141, 0xF, 0xF, true)); }
        else if (m == 8) { z0 += __int_as_float(__builtin_amdgcn_update_dpp(0, __float_as_int(z0), 0x128, 0xF, 0xF, true));
                           z1 += __int_as_float(__builtin_amdgcn_update_dpp(0, __float_as_int(z1), 0x128, 0xF, 0xF, true));
                           z2 += __int_as_float(__builtin_amdgcn_update_dpp(0, __float_as_int(z2), 0x128, 0xF, 0xF, true));
                           z3 += __int_as_float(__builtin_amdgcn_update_dpp(0, __float_as_int(z3), 0x128, 0xF, 0xF, true)); }
        else if (m == 16){ z0 = fold16_f(z0, a16);
                           z1 = fold16_f(z1, a16);
                           z2 = fold16_f(z2, a16);
                           z3 = fold16_f(z3, a16); }
        else             { z0 = fold32_f(z0, a32);
                           z1 = fold32_f(z1, a32);
                           z2 = fold32_f(z2, a32);
                           z3 = fold32_f(z3, a32); }
    }
    if (lane == 0) {
        out[wid * 4 + 0] = z0 * oscale[0];
        out[wid * 4 + 1] = z1 * oscale[1];
        out[wid * 4 + 2] = z2 * oscale[2];
        out[wid * 4 + 3] = z3 * oscale[3];
    }
#undef SWAPR
}

extern "C" void kernel_launch(void* const* d_in, const int* in_sizes, int n_in,
                              void* d_out, int out_size, void* d_ws, size_t ws_size,
                              hipStream_t stream) {
    const float* x      = (const float*)d_in[0];
    const float* isc    = (const float*)d_in[1];
    const float* w      = (const float*)d_in[2];
    const float* oscale = (const float*)d_in[3];
    float* out = (float*)d_out;

    const int B = in_sizes[0] / OBS;             // 4096
    const int threads = 256;                     // 4 waves -> 4 samples per block
    const int blocks = (B * 64 + threads - 1) / threads;
    qsim_kernel<<<blocks, threads, 0, stream>>>(x, isc, w, oscale, out, B);
}

// Round 6
// 83.862 us; speedup vs baseline: 1.0926x; 1.0097x over previous
//
#include <hip/hip_runtime.h>

// Batched 10-qubit statevector simulator — one 64-lane wave per sample.
// State: 1024 complex amps; s = (r<<6)|lane; qubit q <-> bit (9-q):
//   qubits 0..3 -> register-index bits (16 regs per lane)
//   qubits 4..9 -> lane bits (butterfly exchanges)
// R14 (38.5us): f16x2 state, v_pk_fma_f16 math, fp32 coeffs via readlane,
//   layer-0 product construction, ring-4 folded into epilogue parities.
// R18 POST-MORTEM (regressed): DS->VALU migration in the overlapped gate
//   loop loses on a VALU-issue-bound kernel. permlane only in the tail.
// R19 (87.7, win): pre-packed h2 gate constants, hoisted sign masks,
//   v_dot2 epilogue.
// R20 (86.3, win): M=1/2/4/8 exchanges DPP -> ds_swizzle (VALU -> DS pipe).
// R21 (84.7, win): gate constants via wave-private LDS slab broadcast
//   (160 v_readlane -> 40 ds_read_b128); epilogue sL factoring + packed
//   f2 accumulators.
// R22 (retry — R22a was a compile error: cvt_pkrtz returns __fp16 vector,
//   needs a bitcast to our _Float16-based h2; fixed via memcpy cast):
//   (a) layer-0 construction in packed f32 (v_pk_fma_f32): complex mul
//       4 ops -> 2; state pack via v_cvt_pkrtz_f16_f32 (3 ops -> 1; RTZ
//       on constructed state only, non-compounding, constants stay RNE).
//   (b) ring restructure by commutation: CNOT(9,0) moved BEFORE the bperm
//       (pre-swap ctl = popc(lane)&1, inverted for odd-r pairs because
//       addr_odd's ^32 flips source parity; parity(Gray(l)) == bit0(l)),
//       and next layer's 10 K ds_reads issued BETWEEN pre-swap and bperms.
//       Post-bperm there is now NO dependent VALU block: K returns first
//       (in-order DS), gates consume bperm results with partial waits.
//   (c) M=16 exchange ds_swizzle 0x401F (drops addr-VGPR dependency).
// Ladder: 137 (R0) -> 78 -> 64 -> 48 -> 44.8 -> 41.8 -> 38.5 (f16x2) ->
//   R19 -> R20 -> R21 (steady ~34.6).
// Falsified: extra waves/sample (R8), DS phase staggering (R11), ring
//   folding into gate coeffs (R12), rolled layer loop (R13), __hfma2 (R15),
//   op_sel asm + packed coeffs w/ asm (R16), 2 samples/wave (R17),
//   permlane in hot gate loop (R18: DS->VALU on issue-bound kernel).

constexpr int NQ  = 10;
constexpr int NL  = 5;
constexpr int OBS = 10;

typedef float        f2 __attribute__((ext_vector_type(2)));
typedef _Float16     h2 __attribute__((ext_vector_type(2)));
typedef unsigned int u2 __attribute__((ext_vector_type(2)));
typedef int          i4 __attribute__((ext_vector_type(4)));

__device__ __forceinline__ float readlane_f(float v, int l) {
    return __int_as_float(__builtin_amdgcn_readlane(__float_as_int(v), l));
}
__device__ __forceinline__ int h2_to_i(h2 v) { int i; __builtin_memcpy(&i, &v, 4); return i; }
__device__ __forceinline__ h2  i_to_h2(int i) { h2 v; __builtin_memcpy(&v, &i, 4); return v; }

__device__ __forceinline__ h2 bperm_h2(int byte_addr, h2 v) {
    return i_to_h2(__builtin_amdgcn_ds_bpermute(byte_addr, h2_to_i(v)));
}
// ds_swizzle BitMode: offset = (xor<<10)|(or<<5)|and ; and=0x1F keeps all
// 5 lane bits, xor=M flips. Per 32-lane half -> exact for M<32 (incl 16).
template <int M>
__device__ __forceinline__ h2 swz_h2(h2 v) {
    return i_to_h2(__builtin_amdgcn_ds_swizzle(h2_to_i(v), (M << 10) | 0x1F));
}

#if __has_builtin(__builtin_amdgcn_permlane16_swap) && __has_builtin(__builtin_amdgcn_permlane32_swap)
#define HAVE_PERMLANE_SWAP 1
#else
#define HAVE_PERMLANE_SWAP 0
#endif

// xor-exchange across lanes; M compile-time -> branches fold.
// ALL gate-loop exchanges live on the DS pipe (overlapped region; VALU is
// the bottleneck pipe — R18/R20 pipe-balance lesson).
__device__ __forceinline__ h2 xor_lane(h2 v, int M, int a32) {
    switch (M) {
    case 1:  return swz_h2<1>(v);
    case 2:  return swz_h2<2>(v);
    case 4:  return swz_h2<4>(v);
    case 8:  return swz_h2<8>(v);
    case 16: return swz_h2<16>(v);
    default: return bperm_h2(a32, v);              // 32 crosses the half
    }
}

// Epilogue folds: z + z[lane^M] via permlane-swap (VALU) — tail is
// latency-exposed, permlane (~4cy) beats a DS round-trip (~30cy).
// ret0 + ret1 == v[lane&~M] + v[lane|M] regardless of half convention.
__device__ __forceinline__ float fold16_f(float z, int a16) {
#if HAVE_PERMLANE_SWAP
    u2 r = __builtin_amdgcn_permlane16_swap(
        __float_as_uint(z), __float_as_uint(z), false, false);
    return __uint_as_float(r[0]) + __uint_as_float(r[1]);
#else
    return z + __int_as_float(__builtin_amdgcn_ds_bpermute(a16, __float_as_int(z)));
#endif
}
__device__ __forceinline__ float fold32_f(float z, int a32) {
#if HAVE_PERMLANE_SWAP
    u2 r = __builtin_amdgcn_permlane32_swap(
        __float_as_uint(z), __float_as_uint(z), false, false);
    return __uint_as_float(r[0]) + __uint_as_float(r[1]);
#else
    return z + __int_as_float(__builtin_amdgcn_ds_bpermute(a32, __float_as_int(z)));
#endif
}

__device__ __forceinline__ h2 mk_h2(float a, float b) {
    h2 r; r.x = (_Float16)a; r.y = (_Float16)b; return r;
}
// single-instruction f32x2 -> f16x2 pack (RTZ); used for STATE only.
// NOTE: builtin returns __fp16 ext_vector(2) — bitcast to our h2.
__device__ __forceinline__ h2 pk_h2(float a, float b) {
#if __has_builtin(__builtin_amdgcn_cvt_pkrtz)
    auto t = __builtin_amdgcn_cvt_pkrtz(a, b);
    h2 r; __builtin_memcpy(&r, &t, 4); return r;
#else
    return mk_h2(a, b);
#endif
}
__device__ __forceinline__ h2 xor_h2(h2 v, int m) {
    return i_to_h2(h2_to_i(v) ^ m);
}

__global__ __launch_bounds__(256, 4) void qsim_kernel(
    const float* __restrict__ x,       // (B, 10)
    const float* __restrict__ isc,     // (5, 20)
    const float* __restrict__ w,       // (5, 20)
    const float* __restrict__ oscale,  // (4)
    float* __restrict__ out,           // (B, 4)
    int B)
{
    const int lane  = threadIdx.x & 63;
    const int wslot = threadIdx.x >> 6;            // wave index within block
    const int wid   = (blockIdx.x * blockDim.x + threadIdx.x) >> 6;
    if (wid >= B) return;

    // per-wave constant slab: 50 gates x 4 dwords (pkUU,pkUI,pkVV,pkVI)
    __shared__ int ldsK[4][50 * 4];

    // ---- lane-parallel gate-coefficient computation (gates 0..49), fp32 ----
    // Each lane owns one gate; packs the 4 h2 constants and stores them to
    // the wave-private LDS slab with ONE ds_write_b128. No barrier: the
    // only consumer is this same wave (same-wave DS ordering via lgkmcnt).
    float cUR, cUI, cVR, cVI;
    {
        const int g   = (lane < 50) ? lane : 49;
        const int q   = g % 10;
        const int lyr = g / 10;
        const float xq    = x[wid * OBS + q];
        const float alpha = isc[lyr * 2 * NQ + q]      * xq;
        const float beta  = isc[lyr * 2 * NQ + NQ + q] * xq;
        const float gamma = w[lyr * 2 * NQ + q];
        const float delta = w[lyr * 2 * NQ + NQ + q];
        float sa, ca, sp, cp, sd, cd;
        __sincosf(0.5f * alpha,          &sa, &ca);
        __sincosf(0.5f * (beta + gamma), &sp, &cp);
        __sincosf(0.5f * delta,          &sd, &cd);
        const float A = cd * ca, Bt = sd * sa;
        const float C = cd * sa, D  = sd * ca;
        cUR = (A - Bt) * cp;
        cUI = -(A + Bt) * sp;
        cVR = (C + D) * cp;
        cVI = (C - D) * sp;
        if (lane < 50) {
            i4 pk;
            pk.x = h2_to_i(mk_h2(cUR,  cUR));      // kUU = (u, u)
            pk.y = h2_to_i(mk_h2(-cUI, cUI));      // kUI = (-ui, ui)
            pk.z = h2_to_i(mk_h2(cVR,  cVR));      // kVV = (vr, vr)
            pk.w = h2_to_i(mk_h2(-cVI, cVI));      // kVI = (-vi, vi)
            *reinterpret_cast<i4*>(&ldsK[wslot][lane * 4]) = pk;
        }
    }

    // hoisted addresses / predicates
    const int a16 = (lane ^ 16) * 4;               // fold16 fallback only
    const int a32 = (lane ^ 32) * 4;
    const int cnot_src  = (lane ^ (lane >> 1));    // Gray code
    const int addr_even = cnot_src * 4;            // r bit0 == 0
    const int addr_odd  = (cnot_src ^ 32) * 4;     // r bit0 == 1 (CNOT(3,4))
    // CNOT(9,0) commuted BEFORE the bperm: parity(Gray(l)) == bit0(l), and
    // addr_odd's ^32 flips source parity -> invert control for odd-r pairs.
    const bool ctlE = (__popc(lane) & 1) != 0;     // even-r pair control
    const bool ctlO = !ctlE;                       // odd-r pair control

    // hoisted per-lane sign masks for lane-bit gates:
    // smP[q-4] = (lane has bit M set) ? 0x80008000 : 0  (kPI = kUI ^ smP,
    // kQR = (-kVV) ^ smP) — computed once, reused across 4 layers.
    int smP[6];
#pragma unroll
    for (int qq = 0; qq < 6; ++qq) {
        const int M = 1 << (5 - qq);               // q=4..9 -> M=32..1
        smP[qq] = (lane & M) ? (int)0x80008000 : 0;
    }

    h2 c[16];
    h2 Kc[NQ][4];  // current layer's gate constants (prefetched during ring)

    // broadcast-load one layer's 10 gate-constant quads from the
    // wave-private LDS slab (wave-uniform addr -> conflict-free broadcast).
    auto loadK = [&](int lyr) {
#pragma unroll
        for (int q = 0; q < NQ; ++q) {
            const i4 pk = *reinterpret_cast<const i4*>(
                &ldsK[wslot][(lyr * NQ + q) * 4]);
            Kc[q][0] = i_to_h2(pk.x);              // kUU
            Kc[q][1] = i_to_h2(pk.y);              // kUI
            Kc[q][2] = i_to_h2(pk.z);              // kVV
            Kc[q][3] = i_to_h2(pk.w);              // kVI
        }
    };

    // ===== layer 0: direct product-state construction (packed f32) =====
    // amp(s) = prod_q (bit_q(s) ? v_q : u_q), gate column (u,v)=U|0>.
    // complex mul as 2 pk ops: out = (A.x,A.x)*F1 + (A.y,A.y)*F2,
    // F1=(fr,fi), F2=(-fi,fr).
    {
        f2 L = (f2){1.f, 0.f};
#pragma unroll
        for (int q = 4; q < 10; ++q) {
            const float ur = readlane_f(cUR, q), ui = readlane_f(cUI, q);
            const float vr = readlane_f(cVR, q), vi = readlane_f(cVI, q);
            const int M = 1 << (9 - q);
            const bool b = (lane & M) != 0;
            const f2 F1 = (f2){ b ? vr : ur,  b ? vi : ui };
            const f2 F2 = (f2){ -F1.y, F1.x };
            L = (f2){L.x, L.x} * F1 + (f2){L.y, L.y} * F2;
        }
        f2 cf[16];
        cf[0] = L;
#pragma unroll
        for (int r = 1; r < 16; ++r) cf[r] = (f2){0.f, 0.f};
#pragma unroll
        for (int q = 3; q >= 0; --q) {
            const int m = 1 << (3 - q);
            const float ur = readlane_f(cUR, q), ui = readlane_f(cUI, q);
            const float vr = readlane_f(cVR, q), vi = readlane_f(cVI, q);
            const f2 U1 = (f2){ur, ui}, U2 = (f2){-ui, ur};
            const f2 V1 = (f2){vr, vi}, V2 = (f2){-vi, vr};
#pragma unroll
            for (int r0 = 0; r0 < 16; ++r0) {
                if (r0 >= m) continue;
                const f2 s  = cf[r0];
                const f2 sx = (f2){s.x, s.x}, sy = (f2){s.y, s.y};
                cf[r0 | m] = sx * V1 + sy * V2;
                cf[r0]     = sx * U1 + sy * U2;
            }
        }
#pragma unroll
        for (int r = 0; r < 16; ++r) c[r] = pk_h2(cf[r].x, cf[r].y);
    }

#define SWAPR(i, j) { h2 _t = c[i]; c[i] = c[j]; c[j] = _t; }
    // Ring: renames -> CNOT(9,0) pre-swap -> K prefetch (DS, returns
    // before bperms) -> fused lane-CNOT bperms. Nothing blocks after.
#define RING(nextL)                                                     \
    {                                                                   \
        SWAPR(8, 12) SWAPR(9, 13) SWAPR(10, 14) SWAPR(11, 15)           \
        SWAPR(4, 6)  SWAPR(5, 7)  SWAPR(12, 14) SWAPR(13, 15)           \
        SWAPR(2, 3)  SWAPR(6, 7)  SWAPR(10, 11) SWAPR(14, 15)           \
        _Pragma("unroll")                                               \
        for (int r = 0; r < 8; ++r) {                                   \
            const bool ct = (r & 1) ? ctlO : ctlE;                      \
            const h2 t0 = c[r], t1 = c[r + 8];                          \
            c[r]     = ct ? t1 : t0;                                    \
            c[r + 8] = ct ? t0 : t1;                                    \
        }                                                               \
        loadK(nextL);                                                   \
        _Pragma("unroll")                                               \
        for (int r = 0; r < 16; ++r) {                                  \
            const int addr = (r & 1) ? addr_odd : addr_even;            \
            c[r] = bperm_h2(addr, c[r]);                                \
        }                                                               \
    }

    RING(1)   // ring after layer 0; prefetches layer-1 constants

    for (int layer = 1; layer < NL; ++layer) {
        // ---- fused single-qubit unitaries, constants in Kc ----
#pragma unroll
        for (int q = 0; q < NQ; ++q) {
            const h2 kUU = Kc[q][0];
            const h2 kUI = Kc[q][1];
            const h2 kVV = Kc[q][2];
            const h2 kVI = Kc[q][3];

            if (q < 4) {
                // register-bit qubit: pair stride m inside the lane.
                // c[r0] = u*c0 - conj(v)*c1 ; c[r1] = v*c0 + conj(u)*c1
                // negations fold into pk_fma neg_lo/neg_hi modifiers.
                const int m = 1 << (3 - q);
#pragma unroll
                for (int r0 = 0; r0 < 16; ++r0) {
                    if (r0 & m) continue;
                    const int r1 = r0 | m;
                    const h2 c0 = c[r0], c1 = c[r1];
                    const h2 c0s = c0.yx, c1s = c1.yx;
                    c[r0] = kUU*c0 + kUI*c0s - kVV*c1 + kVI*c1s;
                    c[r1] = kVV*c0 + kVI*c0s + kUU*c1 - kUI*c1s;
                }
            } else {
                // lane-bit qubit: butterfly exchange with lane^M (DS pipe).
                // per-lane signed constants via 2 xors with hoisted mask.
                const int  M  = 1 << (9 - q);
                const int  sm = smP[q - 4];
                const h2 kPI = xor_h2(kUI, sm);          // bit? -kUI : kUI
                const h2 kQR = xor_h2(-kVV, sm);         // bit?  kVV : -kVV
#pragma unroll
                for (int r = 0; r < 16; ++r) {
                    const h2 mv = c[r];
                    const h2 pv = xor_lane(mv, M, a32);
                    c[r] = kUU*mv + kPI*mv.yx + kQR*pv + kVI*pv.yx;
                }
            }
        }
        // ---- CNOT ring (skipped on last layer; folded into epilogue) ----
        if (layer == 1) { RING(2) }
        else if (layer == 2) { RING(3) }
        else if (layer == 3) { RING(4) }
    }

    // ---- epilogue (fp32): <Z_i> after the (virtual) final ring ----
    // (Cb)_0 = q1+..+q9 -> reg bits r2,r1,r0 + all 6 lane bits
    // (Cb)_1 = q0+q1 -> r3,r2 ; (Cb)_2 -> r3,r2,r1 ; (Cb)_3 -> r3..r0
    // sL (=+-1, lane parity) factored OUT of the z0 loop (exact); packed
    // f2 accumulators -> v_pk_add_f32 with compile-time neg modifiers.
    f2 Z01 = (f2){0.f, 0.f}, Z23 = (f2){0.f, 0.f};
#pragma unroll
    for (int r = 0; r < 16; ++r) {
#if __has_builtin(__builtin_amdgcn_fdot2)
        const float pv = __builtin_amdgcn_fdot2(c[r], c[r], 0.0f, false);
#else
        const float cr = (float)c[r].x, ci = (float)c[r].y;
        const float pv = cr * cr + ci * ci;
#endif
        Z01 += (f2){ (__popc(r & 7)  & 1) ? -pv : pv,
                     (__popc(r & 12) & 1) ? -pv : pv };
        Z23 += (f2){ (__popc(r & 14) & 1) ? -pv : pv,
                     (__popc(r & 15) & 1) ? -pv : pv };
    }
    const float sL = ctlE ? -1.f : 1.f;
    float z0 = Z01.x * sL, z1 = Z01.y, z2 = Z23.x, z3 = Z23.y;
    // f32 xor-lane reduction (DPP for 1,2,4,8; permlane-swap folds for 16,32)
#pragma unroll
    for (int m = 1; m < 64; m <<= 1) {
        if (m == 1)      { z0 += __int_as_float(__builtin_amdgcn_update_dpp(0, __float_as_int(z0), 0xB1, 0xF, 0xF, true));
                           z1 += __int_as_float(__builtin_amdgcn_update_dpp(0, __float_as_int(z1), 0xB1, 0xF, 0xF, true));
                           z2 += __int_as_float(__builtin_amdgcn_update_dpp(0, __float_as_int(z2), 0xB1, 0xF, 0xF, true));
                           z3 += __int_as_float(__builtin_amdgcn_update_dpp(0, __float_as_int(z3), 0xB1, 0xF, 0xF, true)); }
        else if (m == 2) { z0 += __int_as_float(__builtin_amdgcn_update_dpp(0, __float_as_int(z0), 0x4E, 0xF, 0xF, true));
                           z1 += __int_as_float(__builtin_amdgcn_update_dpp(0, __float_as_int(z1), 0x4E, 0xF, 0xF, true));
                           z2 += __int_as_float(__builtin_amdgcn_update_dpp(0, __float_as_int(z2), 0x4E, 0xF, 0xF, true));
                           z3 += __int_as_float(__builtin_amdgcn_update_dpp(0, __float_as_int(z3), 0x4E, 0xF, 0xF, true)); }
        else if (m == 4) { z0 += __int_as_float(__builtin_amdgcn_update_dpp(0, __builtin_amdgcn_update_dpp(0, __float_as_int(z0), 0x1B, 0xF, 0xF, true), 0x141, 0xF, 0xF, true));
                           z1 += __int_as_float(__builtin_amdgcn_update_dpp(0, __builtin_amdgcn_update_dpp(0, __float_as_int(z1), 0x1B, 0xF, 0xF, true), 0x141, 0xF, 0xF, true));
                           z2 += __int_as_float(__builtin_amdgcn_update_dpp(0, __builtin_amdgcn_update_dpp(0, __float_as_int(z2), 0x1B, 0xF, 0xF, true), 0x141, 0xF, 0xF, true));
                           z3 += __int_as_float(__builtin_amdgcn_update_dpp(0, __builtin_amdgcn_update_dpp(0, __float_as_int(z3), 0x1B, 0xF, 0xF, true), 0x141, 0xF, 0xF, true)); }
        else if (m == 8) { z0 += __int_as_float(__builtin_amdgcn_update_dpp(0, __float_as_int(z0), 0x128, 0xF, 0xF, true));
                           z1 += __int_as_float(__builtin_amdgcn_update_dpp(0, __float_as_int(z1), 0x128, 0xF, 0xF, true));
                           z2 += __int_as_float(__builtin_amdgcn_update_dpp(0, __float_as_int(z2), 0x128, 0xF, 0xF, true));
                           z3 += __int_as_float(__builtin_amdgcn_update_dpp(0, __float_as_int(z3), 0x128, 0xF, 0xF, true)); }
        else if (m == 16){ z0 = fold16_f(z0, a16);
                           z1 = fold16_f(z1, a16);
                           z2 = fold16_f(z2, a16);
                           z3 = fold16_f(z3, a16); }
        else             { z0 = fold32_f(z0, a32);
                           z1 = fold32_f(z1, a32);
                           z2 = fold32_f(z2, a32);
                           z3 = fold32_f(z3, a32); }
    }
    if (lane == 0) {
        out[wid * 4 + 0] = z0 * oscale[0];
        out[wid * 4 + 1] = z1 * oscale[1];
        out[wid * 4 + 2] = z2 * oscale[2];
        out[wid * 4 + 3] = z3 * oscale[3];
    }
#undef RING
#undef SWAPR
}

extern "C" void kernel_launch(void* const* d_in, const int* in_sizes, int n_in,
                              void* d_out, int out_size, void* d_ws, size_t ws_size,
                              hipStream_t stream) {
    const float* x      = (const float*)d_in[0];
    const float* isc    = (const float*)d_in[1];
    const float* w      = (const float*)d_in[2];
    const float* oscale = (const float*)d_in[3];
    float* out = (float*)d_out;

    const int B = in_sizes[0] / OBS;             // 4096
    const int threads = 256;                     // 4 waves -> 4 samples per block
    const int blocks = (B * 64 + threads - 1) / threads;
    qsim_kernel<<<blocks, threads, 0, stream>>>(x, isc, w, oscale, out, B);
}

// Round 7
// 83.501 us; speedup vs baseline: 1.0973x; 1.0043x over previous
//
#include <hip/hip_runtime.h>

// Batched 10-qubit statevector simulator — one 64-lane wave per sample.
// State: 1024 complex amps; s = (r<<6)|lane; qubit q <-> bit (9-q):
//   qubits 0..3 -> register-index bits (16 regs per lane)
//   qubits 4..9 -> lane bits (butterfly exchanges)
// R14 (38.5us): f16x2 state, v_pk_fma_f16 math, fp32 coeffs via readlane,
//   layer-0 product construction, ring-4 folded into epilogue parities.
// R18 POST-MORTEM (regressed): DS->VALU migration in the overlapped gate
//   loop loses on a VALU-issue-bound kernel. permlane only in the tail.
// R19 (87.7, win): pre-packed h2 gate constants, hoisted sign masks,
//   v_dot2 epilogue.
// R20 (86.3, win): M=1/2/4/8 exchanges DPP -> ds_swizzle (VALU -> DS pipe).
// R21 (84.7, win): gate constants via wave-private LDS slab broadcast;
//   epilogue sL factoring + packed f2 accumulators.
// R22 (83.9, win): packed-f32 layer-0 + cvt_pkrtz state pack; ring
//   restructure (CNOT(9,0) commuted pre-bperm, K prefetch in ring);
//   M=16 via ds_swizzle.
// R23 (this round): tail overlap via OBSERVABLE COMMUTATION.
//   After the virtual-ring fold, Cb1=(q0,q1), Cb2=(q0..2), Cb3=(q0..3)
//   are reg-qubit-only; only Cb0 touches q4..9. Layer-4's six lane-bit
//   gates commute with Cb1..3 -> z1,z2,z3 are computed from the state
//   BEFORE those gates (exact), breaking the dependency so their sums +
//   DPP reduction chains schedule into the lane-gates' DS-wait stalls.
//   z0 gets its own dot2 pass after the gates (+32 ops, the price of
//   overlap). Micro: oscale float4 load hoisted to prologue (hides ~200cy
//   tail latency), single dwordx4 store, pre-flipped smN mask kills the
//   per-lane-gate -kVV negation.
//   Pre-committed read: delta < 0.3us => stall/tail angle exhausted.
// Ladder: 137 (R0) -> 78 -> 64 -> 48 -> 44.8 -> 41.8 -> 38.5 (f16x2) ->
//   R19 -> R20 -> R21 -> R22 (steady ~33.9).
// Falsified: extra waves/sample (R8), DS phase staggering (R11), ring
//   folding into gate coeffs (R12), rolled layer loop (R13), __hfma2 (R15),
//   op_sel asm + packed coeffs w/ asm (R16), 2 samples/wave (R17),
//   permlane in hot gate loop (R18: DS->VALU on issue-bound kernel).

constexpr int NQ  = 10;
constexpr int NL  = 5;
constexpr int OBS = 10;

typedef float        f2 __attribute__((ext_vector_type(2)));
typedef float        f4 __attribute__((ext_vector_type(4)));
typedef _Float16     h2 __attribute__((ext_vector_type(2)));
typedef unsigned int u2 __attribute__((ext_vector_type(2)));
typedef int          i4 __attribute__((ext_vector_type(4)));

__device__ __forceinline__ float readlane_f(float v, int l) {
    return __int_as_float(__builtin_amdgcn_readlane(__float_as_int(v), l));
}
__device__ __forceinline__ int h2_to_i(h2 v) { int i; __builtin_memcpy(&i, &v, 4); return i; }
__device__ __forceinline__ h2  i_to_h2(int i) { h2 v; __builtin_memcpy(&v, &i, 4); return v; }

__device__ __forceinline__ h2 bperm_h2(int byte_addr, h2 v) {
    return i_to_h2(__builtin_amdgcn_ds_bpermute(byte_addr, h2_to_i(v)));
}
// ds_swizzle BitMode: offset = (xor<<10)|(or<<5)|and ; and=0x1F keeps all
// 5 lane bits, xor=M flips. Per 32-lane half -> exact for M<32 (incl 16).
template <int M>
__device__ __forceinline__ h2 swz_h2(h2 v) {
    return i_to_h2(__builtin_amdgcn_ds_swizzle(h2_to_i(v), (M << 10) | 0x1F));
}

#if __has_builtin(__builtin_amdgcn_permlane16_swap) && __has_builtin(__builtin_amdgcn_permlane32_swap)
#define HAVE_PERMLANE_SWAP 1
#else
#define HAVE_PERMLANE_SWAP 0
#endif

// xor-exchange across lanes; M compile-time -> branches fold.
// ALL gate-loop exchanges live on the DS pipe (overlapped region; VALU is
// the bottleneck pipe — R18/R20 pipe-balance lesson).
__device__ __forceinline__ h2 xor_lane(h2 v, int M, int a32) {
    switch (M) {
    case 1:  return swz_h2<1>(v);
    case 2:  return swz_h2<2>(v);
    case 4:  return swz_h2<4>(v);
    case 8:  return swz_h2<8>(v);
    case 16: return swz_h2<16>(v);
    default: return bperm_h2(a32, v);              // 32 crosses the half
    }
}

// Epilogue folds: z + z[lane^M] via permlane-swap (VALU) — tail is
// latency-exposed, permlane (~4cy) beats a DS round-trip (~30cy).
// ret0 + ret1 == v[lane&~M] + v[lane|M] regardless of half convention.
__device__ __forceinline__ float fold16_f(float z, int a16) {
#if HAVE_PERMLANE_SWAP
    u2 r = __builtin_amdgcn_permlane16_swap(
        __float_as_uint(z), __float_as_uint(z), false, false);
    return __uint_as_float(r[0]) + __uint_as_float(r[1]);
#else
    return z + __int_as_float(__builtin_amdgcn_ds_bpermute(a16, __float_as_int(z)));
#endif
}
__device__ __forceinline__ float fold32_f(float z, int a32) {
#if HAVE_PERMLANE_SWAP
    u2 r = __builtin_amdgcn_permlane32_swap(
        __float_as_uint(z), __float_as_uint(z), false, false);
    return __uint_as_float(r[0]) + __uint_as_float(r[1]);
#else
    return z + __int_as_float(__builtin_amdgcn_ds_bpermute(a32, __float_as_int(z)));
#endif
}

__device__ __forceinline__ h2 mk_h2(float a, float b) {
    h2 r; r.x = (_Float16)a; r.y = (_Float16)b; return r;
}
// single-instruction f32x2 -> f16x2 pack (RTZ); used for STATE only.
// NOTE: builtin returns __fp16 ext_vector(2) — bitcast to our h2.
__device__ __forceinline__ h2 pk_h2(float a, float b) {
#if __has_builtin(__builtin_amdgcn_cvt_pkrtz)
    auto t = __builtin_amdgcn_cvt_pkrtz(a, b);
    h2 r; __builtin_memcpy(&r, &t, 4); return r;
#else
    return mk_h2(a, b);
#endif
}
__device__ __forceinline__ h2 xor_h2(h2 v, int m) {
    return i_to_h2(h2_to_i(v) ^ m);
}
__device__ __forceinline__ float dot2_f(h2 v) {
#if __has_builtin(__builtin_amdgcn_fdot2)
    return __builtin_amdgcn_fdot2(v, v, 0.0f, false);
#else
    const float cr = (float)v.x, ci = (float)v.y;
    return cr * cr + ci * ci;
#endif
}

__global__ __launch_bounds__(256, 4) void qsim_kernel(
    const float* __restrict__ x,       // (B, 10)
    const float* __restrict__ isc,     // (5, 20)
    const float* __restrict__ w,       // (5, 20)
    const float* __restrict__ oscale,  // (4)
    float* __restrict__ out,           // (B, 4)
    int B)
{
    const int lane  = threadIdx.x & 63;
    const int wslot = threadIdx.x >> 6;            // wave index within block
    const int wid   = (blockIdx.x * blockDim.x + threadIdx.x) >> 6;
    if (wid >= B) return;

    // hoisted output-scale load: issued at kernel start, consumed at the
    // very end -> its global latency hides under the whole body.
    const f4 osc = *reinterpret_cast<const f4*>(oscale);

    // per-wave constant slab: 50 gates x 4 dwords (pkUU,pkUI,pkVV,pkVI)
    __shared__ int ldsK[4][50 * 4];

    // ---- lane-parallel gate-coefficient computation (gates 0..49), fp32 ----
    // Each lane owns one gate; packs the 4 h2 constants and stores them to
    // the wave-private LDS slab with ONE ds_write_b128. No barrier: the
    // only consumer is this same wave (same-wave DS ordering via lgkmcnt).
    float cUR, cUI, cVR, cVI;
    {
        const int g   = (lane < 50) ? lane : 49;
        const int q   = g % 10;
        const int lyr = g / 10;
        const float xq    = x[wid * OBS + q];
        const float alpha = isc[lyr * 2 * NQ + q]      * xq;
        const float beta  = isc[lyr * 2 * NQ + NQ + q] * xq;
        const float gamma = w[lyr * 2 * NQ + q];
        const float delta = w[lyr * 2 * NQ + NQ + q];
        float sa, ca, sp, cp, sd, cd;
        __sincosf(0.5f * alpha,          &sa, &ca);
        __sincosf(0.5f * (beta + gamma), &sp, &cp);
        __sincosf(0.5f * delta,          &sd, &cd);
        const float A = cd * ca, Bt = sd * sa;
        const float C = cd * sa, D  = sd * ca;
        cUR = (A - Bt) * cp;
        cUI = -(A + Bt) * sp;
        cVR = (C + D) * cp;
        cVI = (C - D) * sp;
        if (lane < 50) {
            i4 pk;
            pk.x = h2_to_i(mk_h2(cUR,  cUR));      // kUU = (u, u)
            pk.y = h2_to_i(mk_h2(-cUI, cUI));      // kUI = (-ui, ui)
            pk.z = h2_to_i(mk_h2(cVR,  cVR));      // kVV = (vr, vr)
            pk.w = h2_to_i(mk_h2(-cVI, cVI));      // kVI = (-vi, vi)
            *reinterpret_cast<i4*>(&ldsK[wslot][lane * 4]) = pk;
        }
    }

    // hoisted addresses / predicates
    const int a16 = (lane ^ 16) * 4;               // fold16 fallback only
    const int a32 = (lane ^ 32) * 4;
    const int cnot_src  = (lane ^ (lane >> 1));    // Gray code
    const int addr_even = cnot_src * 4;            // r bit0 == 0
    const int addr_odd  = (cnot_src ^ 32) * 4;     // r bit0 == 1 (CNOT(3,4))
    // CNOT(9,0) commuted BEFORE the bperm: parity(Gray(l)) == bit0(l), and
    // addr_odd's ^32 flips source parity -> invert control for odd-r pairs.
    const bool ctlE = (__popc(lane) & 1) != 0;     // even-r pair control
    const bool ctlO = !ctlE;                       // odd-r pair control

    // hoisted per-lane sign masks for lane-bit gates:
    // smP: kPI = kUI ^ smP ; smN = smP ^ 0x80008000: kQR = kVV ^ smN
    // (pre-flipped -> no runtime -kVV negation).
    int smP[6], smN[6];
#pragma unroll
    for (int qq = 0; qq < 6; ++qq) {
        const int M = 1 << (5 - qq);               // q=4..9 -> M=32..1
        smP[qq] = (lane & M) ? (int)0x80008000 : 0;
        smN[qq] = smP[qq] ^ (int)0x80008000;
    }

    h2 c[16];
    h2 Kc[NQ][4];  // current layer's gate constants (prefetched during ring)

    // broadcast-load one layer's 10 gate-constant quads from the
    // wave-private LDS slab (wave-uniform addr -> conflict-free broadcast).
    auto loadK = [&](int lyr) {
#pragma unroll
        for (int q = 0; q < NQ; ++q) {
            const i4 pk = *reinterpret_cast<const i4*>(
                &ldsK[wslot][(lyr * NQ + q) * 4]);
            Kc[q][0] = i_to_h2(pk.x);              // kUU
            Kc[q][1] = i_to_h2(pk.y);              // kUI
            Kc[q][2] = i_to_h2(pk.z);              // kVV
            Kc[q][3] = i_to_h2(pk.w);              // kVI
        }
    };

    // ===== layer 0: direct product-state construction (packed f32) =====
    // amp(s) = prod_q (bit_q(s) ? v_q : u_q), gate column (u,v)=U|0>.
    {
        f2 L = (f2){1.f, 0.f};
#pragma unroll
        for (int q = 4; q < 10; ++q) {
            const float ur = readlane_f(cUR, q), ui = readlane_f(cUI, q);
            const float vr = readlane_f(cVR, q), vi = readlane_f(cVI, q);
            const int M = 1 << (9 - q);
            const bool b = (lane & M) != 0;
            const f2 F1 = (f2){ b ? vr : ur,  b ? vi : ui };
            const f2 F2 = (f2){ -F1.y, F1.x };
            L = (f2){L.x, L.x} * F1 + (f2){L.y, L.y} * F2;
        }
        f2 cf[16];
        cf[0] = L;
#pragma unroll
        for (int r = 1; r < 16; ++r) cf[r] = (f2){0.f, 0.f};
#pragma unroll
        for (int q = 3; q >= 0; --q) {
            const int m = 1 << (3 - q);
            const float ur = readlane_f(cUR, q), ui = readlane_f(cUI, q);
            const float vr = readlane_f(cVR, q), vi = readlane_f(cVI, q);
            const f2 U1 = (f2){ur, ui}, U2 = (f2){-ui, ur};
            const f2 V1 = (f2){vr, vi}, V2 = (f2){-vi, vr};
#pragma unroll
            for (int r0 = 0; r0 < 16; ++r0) {
                if (r0 >= m) continue;
                const f2 s  = cf[r0];
                const f2 sx = (f2){s.x, s.x}, sy = (f2){s.y, s.y};
                cf[r0 | m] = sx * V1 + sy * V2;
                cf[r0]     = sx * U1 + sy * U2;
            }
        }
#pragma unroll
        for (int r = 0; r < 16; ++r) c[r] = pk_h2(cf[r].x, cf[r].y);
    }

#define SWAPR(i, j) { h2 _t = c[i]; c[i] = c[j]; c[j] = _t; }
    // Ring: renames -> CNOT(9,0) pre-swap -> K prefetch (DS, returns
    // before bperms) -> fused lane-CNOT bperms. Nothing blocks after.
#define RING(nextL)                                                     \
    {                                                                   \
        SWAPR(8, 12) SWAPR(9, 13) SWAPR(10, 14) SWAPR(11, 15)           \
        SWAPR(4, 6)  SWAPR(5, 7)  SWAPR(12, 14) SWAPR(13, 15)           \
        SWAPR(2, 3)  SWAPR(6, 7)  SWAPR(10, 11) SWAPR(14, 15)           \
        _Pragma("unroll")                                               \
        for (int r = 0; r < 8; ++r) {                                   \
            const bool ct = (r & 1) ? ctlO : ctlE;                      \
            const h2 t0 = c[r], t1 = c[r + 8];                          \
            c[r]     = ct ? t1 : t0;                                    \
            c[r + 8] = ct ? t0 : t1;                                    \
        }                                                               \
        loadK(nextL);                                                   \
        _Pragma("unroll")                                               \
        for (int r = 0; r < 16; ++r) {                                  \
            const int addr = (r & 1) ? addr_odd : addr_even;            \
            c[r] = bperm_h2(addr, c[r]);                                \
        }                                                               \
    }

    // gate bodies (shared between the main loop and the peeled last layer)
#define REG_GATE(q)                                                     \
    {                                                                   \
        const h2 kUU = Kc[q][0], kUI = Kc[q][1];                        \
        const h2 kVV = Kc[q][2], kVI = Kc[q][3];                        \
        const int m = 1 << (3 - (q));                                   \
        _Pragma("unroll")                                               \
        for (int r0 = 0; r0 < 16; ++r0) {                               \
            if (r0 & m) continue;                                       \
            const int r1 = r0 | m;                                      \
            const h2 c0 = c[r0], c1 = c[r1];                            \
            const h2 c0s = c0.yx, c1s = c1.yx;                          \
            c[r0] = kUU*c0 + kUI*c0s - kVV*c1 + kVI*c1s;                \
            c[r1] = kVV*c0 + kVI*c0s + kUU*c1 - kUI*c1s;                \
        }                                                               \
    }
#define LANE_GATE(q)                                                    \
    {                                                                   \
        const h2 kUU = Kc[q][0];                                        \
        const h2 kVI = Kc[q][3];                                        \
        const int M  = 1 << (9 - (q));                                  \
        const h2 kPI = xor_h2(Kc[q][1], smP[(q) - 4]);                  \
        const h2 kQR = xor_h2(Kc[q][2], smN[(q) - 4]);                  \
        _Pragma("unroll")                                               \
        for (int r = 0; r < 16; ++r) {                                  \
            const h2 mv = c[r];                                         \
            const h2 pv = xor_lane(mv, M, a32);                         \
            c[r] = kUU*mv + kPI*mv.yx + kQR*pv + kVI*pv.yx;             \
        }                                                               \
    }

    RING(1)   // ring after layer 0; prefetches layer-1 constants

    // ---- layers 1..3: full gate set + ring (prefetching next K) ----
    for (int layer = 1; layer < NL - 1; ++layer) {
#pragma unroll
        for (int q = 0; q < 4; ++q) REG_GATE(q)
#pragma unroll
        for (int q = 4; q < NQ; ++q) LANE_GATE(q)
        if (layer == 1) { RING(2) }
        else if (layer == 2) { RING(3) }
        else { RING(4) }
    }

    // ===== layer 4 (last, peeled): reg gates -> z1..3 early -> lane
    // gates -> z0. Gates on q4..9 commute with Cb1..3 (reg-qubit-only
    // observables), so z1..3 measured BEFORE them is exact — and their
    // sums + reduction chains overlap the lane-gates' DS waits.
#pragma unroll
    for (int q = 0; q < 4; ++q) REG_GATE(q)

    // z1..3 partial sums (pre-lane-gate state). Compile-time signs fold
    // into pk_add neg modifiers.
    f2 Z12 = (f2){0.f, 0.f};
    float z3 = 0.f;
#pragma unroll
    for (int r = 0; r < 16; ++r) {
        const float pv = dot2_f(c[r]);
        Z12 += (f2){ (__popc(r & 12) & 1) ? -pv : pv,
                     (__popc(r & 14) & 1) ? -pv : pv };
        z3  += (__popc(r & 15) & 1) ? -pv : pv;
    }
    float z1 = Z12.x, z2 = Z12.y;

    // lane-bit gates of layer 4 (feed z0 only)
#pragma unroll
    for (int q = 4; q < NQ; ++q) LANE_GATE(q)

    // z0 sum (post-gate state); sL (=+-1) factored out (exact).
    float z0 = 0.f;
#pragma unroll
    for (int r = 0; r < 16; ++r) {
        const float pv = dot2_f(c[r]);
        z0 += (__popc(r & 7) & 1) ? -pv : pv;
    }
    const float sL = ctlE ? -1.f : 1.f;
    z0 *= sL;

    // f32 xor-lane reduction (DPP for 1,2,4,8; permlane-swap folds 16,32)
#pragma unroll
    for (int m = 1; m < 64; m <<= 1) {
        if (m == 1)      { z0 += __int_as_float(__builtin_amdgcn_update_dpp(0, __float_as_int(z0), 0xB1, 0xF, 0xF, true));
                           z1 += __int_as_float(__builtin_amdgcn_update_dpp(0, __float_as_int(z1), 0xB1, 0xF, 0xF, true));
                           z2 += __int_as_float(__builtin_amdgcn_update_dpp(0, __float_as_int(z2), 0xB1, 0xF, 0xF, true));
                           z3 += __int_as_float(__builtin_amdgcn_update_dpp(0, __float_as_int(z3), 0xB1, 0xF, 0xF, true)); }
        else if (m == 2) { z0 += __int_as_float(__builtin_amdgcn_update_dpp(0, __float_as_int(z0), 0x4E, 0xF, 0xF, true));
                           z1 += __int_as_float(__builtin_amdgcn_update_dpp(0, __float_as_int(z1), 0x4E, 0xF, 0xF, true));
                           z2 += __int_as_float(__builtin_amdgcn_update_dpp(0, __float_as_int(z2), 0x4E, 0xF, 0xF, true));
                           z3 += __int_as_float(__builtin_amdgcn_update_dpp(0, __float_as_int(z3), 0x4E, 0xF, 0xF, true)); }
        else if (m == 4) { z0 += __int_as_float(__builtin_amdgcn_update_dpp(0, __builtin_amdgcn_update_dpp(0, __float_as_int(z0), 0x1B, 0xF, 0xF, true), 0x141, 0xF, 0xF, true));
                           z1 += __int_as_float(__builtin_amdgcn_update_dpp(0, __builtin_amdgcn_update_dpp(0, __float_as_int(z1), 0x1B, 0xF, 0xF, true), 0x141, 0xF, 0xF, true));
                           z2 += __int_as_float(__builtin_amdgcn_update_dpp(0, __builtin_amdgcn_update_dpp(0, __float_as_int(z2), 0x1B, 0xF, 0xF, true), 0x141, 0xF, 0xF, true));
                           z3 += __int_as_float(__builtin_amdgcn_update_dpp(0, __builtin_amdgcn_update_dpp(0, __float_as_int(z3), 0x1B, 0xF, 0xF, true), 0x141, 0xF, 0xF, true)); }
        else if (m == 8) { z0 += __int_as_float(__builtin_amdgcn_update_dpp(0, __float_as_int(z0), 0x128, 0xF, 0xF, true));
                           z1 += __int_as_float(__builtin_amdgcn_update_dpp(0, __float_as_int(z1), 0x128, 0xF, 0xF, true));
                           z2 += __int_as_float(__builtin_amdgcn_update_dpp(0, __float_as_int(z2), 0x128, 0xF, 0xF, true));
                           z3 += __int_as_float(__builtin_amdgcn_update_dpp(0, __float_as_int(z3), 0x128, 0xF, 0xF, true)); }
        else if (m == 16){ z0 = fold16_f(z0, a16);
                           z1 = fold16_f(z1, a16);
                           z2 = fold16_f(z2, a16);
                           z3 = fold16_f(z3, a16); }
        else             { z0 = fold32_f(z0, a32);
                           z1 = fold32_f(z1, a32);
                           z2 = fold32_f(z2, a32);
                           z3 = fold32_f(z3, a32); }
    }
    if (lane == 0) {
        f4 o;
        o.x = z0 * osc.x; o.y = z1 * osc.y;
        o.z = z2 * osc.z; o.w = z3 * osc.w;
        *reinterpret_cast<f4*>(out + wid * 4) = o;   // one dwordx4 store
    }
#undef LANE_GATE
#undef REG_GATE
#undef RING
#undef SWAPR
}

extern "C" void kernel_launch(void* const* d_in, const int* in_sizes, int n_in,
                              void* d_out, int out_size, void* d_ws, size_t ws_size,
                              hipStream_t stream) {
    const float* x      = (const float*)d_in[0];
    const float* isc    = (const float*)d_in[1];
    const float* w      = (const float*)d_in[2];
    const float* oscale = (const float*)d_in[3];
    float* out = (float*)d_out;

    const int B = in_sizes[0] / OBS;             // 4096
    const int threads = 256;                     // 4 waves -> 4 samples per block
    const int blocks = (B * 64 + threads - 1) / threads;
    qsim_kernel<<<blocks, threads, 0, stream>>>(x, isc, w, oscale, out, B);
}